// Round 1
// 881.074 us; speedup vs baseline: 1.0261x; 1.0261x over previous
//
#include <hip/hip_runtime.h>

// ---- problem constants ----
constexpr int B_ = 8, T_ = 2048, C_ = 1024, H_ = 16, N_ = 64;
constexpr int M_ = B_ * T_;              // 16384 rows
constexpr int FC_ = 4 * C_;              // 4096

typedef __attribute__((ext_vector_type(8))) short bf16x8;
typedef __attribute__((ext_vector_type(4))) float f32x4;
typedef unsigned short ushort_t;
typedef unsigned int uint_t;

__device__ __forceinline__ float bfu2f(ushort_t u) {
    union { uint_t i; float f; } c; c.i = ((uint_t)u) << 16; return c.f;
}
__device__ __forceinline__ ushort_t f2bfu(float f) {
    union { float f; uint_t i; } c; c.f = f;
    uint_t i = c.i;
    uint_t r = i + 0x7FFFu + ((i >> 16) & 1u);   // round-to-nearest-even
    return (ushort_t)(r >> 16);
}

__device__ __forceinline__ void gl_lds16(const void* g, void* l) {
    __builtin_amdgcn_global_load_lds(
        (const __attribute__((address_space(1))) void*)g,
        (__attribute__((address_space(3))) void*)l, 16, 0, 0);
}

// =====================================================================
// fp32 -> bf16 weight converts, folded into 2 launches
// =====================================================================
__global__ __launch_bounds__(256) void f2bf3_kernel(const float* __restrict__ a,
                                                    const float* __restrict__ b,
                                                    const float* __restrict__ c,
                                                    ushort_t* __restrict__ oa,
                                                    ushort_t* __restrict__ ob,
                                                    ushort_t* __restrict__ oc) {
    const float* in = (blockIdx.y == 0) ? a : (blockIdx.y == 1) ? b : c;
    ushort_t* out   = (blockIdx.y == 0) ? oa : (blockIdx.y == 1) ? ob : oc;
    size_t i = ((size_t)blockIdx.x * 256 + threadIdx.x) * 4;
    float4 v = *(const float4*)(in + i);
    uint2 o;
    o.x = (uint_t)f2bfu(v.x) | ((uint_t)f2bfu(v.y) << 16);
    o.y = (uint_t)f2bfu(v.z) | ((uint_t)f2bfu(v.w) << 16);
    *(uint2*)(out + i) = o;
}

__global__ __launch_bounds__(256) void f2bf2_kernel(const float* __restrict__ a,
                                                    const float* __restrict__ b,
                                                    ushort_t* __restrict__ oa,
                                                    ushort_t* __restrict__ ob) {
    const float* in = (blockIdx.y == 0) ? a : b;
    ushort_t* out   = (blockIdx.y == 0) ? oa : ob;
    size_t i = ((size_t)blockIdx.x * 256 + threadIdx.x) * 4;
    float4 v = *(const float4*)(in + i);
    uint2 o;
    o.x = (uint_t)f2bfu(v.x) | ((uint_t)f2bfu(v.y) << 16);
    o.y = (uint_t)f2bfu(v.z) | ((uint_t)f2bfu(v.w) << 16);
    *(uint2*)(out + i) = o;
}

// =====================================================================
// LayerNorm over C=1024, one block per row, output bf16
// =====================================================================
__global__ __launch_bounds__(256) void ln_kernel(const float* __restrict__ x,
                                                 const float* __restrict__ w,
                                                 const float* __restrict__ b,
                                                 ushort_t* __restrict__ out) {
    const int row = blockIdx.x;
    const int tid = threadIdx.x;
    const float* xr = x + (size_t)row * C_;
    float4 xv = ((const float4*)xr)[tid];
    float s  = xv.x + xv.y + xv.z + xv.w;
    float ss = xv.x*xv.x + xv.y*xv.y + xv.z*xv.z + xv.w*xv.w;
#pragma unroll
    for (int off = 32; off; off >>= 1) { s += __shfl_down(s, off); ss += __shfl_down(ss, off); }
    __shared__ float sb[8];
    const int wv = tid >> 6, ln = tid & 63;
    if (ln == 0) { sb[wv] = s; sb[4 + wv] = ss; }
    __syncthreads();
    s  = sb[0] + sb[1] + sb[2] + sb[3];
    ss = sb[4] + sb[5] + sb[6] + sb[7];
    const float mean = s * (1.f / C_);
    const float var  = ss * (1.f / C_) - mean * mean;
    const float rstd = rsqrtf(var + 1e-5f);
    float4 wv4 = ((const float4*)w)[tid];
    float4 bv4 = ((const float4*)b)[tid];
    uint2 o;
    o.x = (uint_t)f2bfu((xv.x - mean) * rstd * wv4.x + bv4.x)
        | ((uint_t)f2bfu((xv.y - mean) * rstd * wv4.y + bv4.y) << 16);
    o.y = (uint_t)f2bfu((xv.z - mean) * rstd * wv4.z + bv4.z)
        | ((uint_t)f2bfu((xv.w - mean) * rstd * wv4.w + bv4.w) << 16);
    ((uint2*)(out + (size_t)row * C_))[tid] = o;
}

// =====================================================================
// gate[m,h] = sigmoid(dot(xx[m,:], w_g[h,:])), xx computed inline
// =====================================================================
__global__ __launch_bounds__(256) void gate_kernel(const ushort_t* __restrict__ h,
                                                   const float* __restrict__ wg,
                                                   float* __restrict__ gate) {
    __shared__ float xr[C_];
    const int row = blockIdx.x;
    const int tid = threadIdx.x;
    const int t = row & (T_ - 1);
    uint2 cu = *(const uint2*)(h + (size_t)row * C_ + tid * 4);
    uint2 pu = make_uint2(0u, 0u);
    if (t > 0) pu = *(const uint2*)(h + (size_t)(row - 1) * C_ + tid * 4);
    xr[tid * 4 + 0] = bfu2f((ushort_t)(pu.x & 0xffffu)) - bfu2f((ushort_t)(cu.x & 0xffffu));
    xr[tid * 4 + 1] = bfu2f((ushort_t)(pu.x >> 16))     - bfu2f((ushort_t)(cu.x >> 16));
    xr[tid * 4 + 2] = bfu2f((ushort_t)(pu.y & 0xffffu)) - bfu2f((ushort_t)(cu.y & 0xffffu));
    xr[tid * 4 + 3] = bfu2f((ushort_t)(pu.y >> 16))     - bfu2f((ushort_t)(cu.y >> 16));
    __syncthreads();
    const int wv = tid >> 6, ln = tid & 63;
#pragma unroll
    for (int hh = 0; hh < 4; ++hh) {
        const int h_ = wv * 4 + hh;
        const float* wrow = wg + (size_t)h_ * C_;
        float acc = 0.f;
#pragma unroll
        for (int i = 0; i < 16; ++i) { int c = i * 64 + ln; acc += xr[c] * wrow[c]; }
#pragma unroll
        for (int off = 32; off; off >>= 1) acc += __shfl_down(acc, off);
        if (ln == 0) gate[(size_t)row * H_ + h_] = 1.f / (1.f + __expf(-acc));
    }
}

// =====================================================================
// wkv fwd+bwd scan (decay 0.5) with 32-step warmup windows, fused combine
// =====================================================================
__global__ __launch_bounds__(128) void wkv_combine_kernel(const float* __restrict__ v,
                                                          const ushort_t* __restrict__ r,
                                                          const float* __restrict__ gate,
                                                          ushort_t* __restrict__ xc) {
    __shared__ float fbuf[128 * 64];
    __shared__ float bbuf[128 * 64];
    const int blk = blockIdx.x;           // b*256 + h*16 + chunk
    const int chunk = blk & 15;
    const int bh = blk >> 4;
    const int h = bh & 15;
    const int b = bh >> 4;
    const int t0 = chunk * 128, t1 = t0 + 128;
    const int tid = threadIdx.x;
    const int n = tid & 63;
    const float* vb = v + (size_t)b * T_ * C_ + h * 64 + n;
    if (tid < 64) {                       // wave 0: forward
        int ts = t0 - 32; if (ts < 0) ts = 0;
        float carry = vb[(size_t)ts * C_];
        if (ts >= t0) fbuf[(ts - t0) * 64 + n] = carry;
        for (int t = ts + 1; t < t1; ++t) {
            carry = 0.5f * (carry + vb[(size_t)t * C_]);
            if (t >= t0) fbuf[(t - t0) * 64 + n] = carry;
        }
    } else {                              // wave 1: backward
        int ts = t1 - 1 + 32; if (ts > T_ - 1) ts = T_ - 1;
        float carry = vb[(size_t)ts * C_];
        if (ts < t1) bbuf[(ts - t0) * 64 + n] = carry;
        for (int t = ts - 1; t >= t0; --t) {
            carry = 0.5f * (carry + vb[(size_t)t * C_]);
            if (t < t1) bbuf[(t - t0) * 64 + n] = carry;
        }
    }
    __syncthreads();
#pragma unroll 4
    for (int i = 0; i < 64; ++i) {
        int idx = i * 128 + tid;
        int tl = idx >> 6, nn = idx & 63;
        size_t mrow = (size_t)b * T_ + (t0 + tl);
        float g = gate[mrow * H_ + h];
        float rr = bfu2f(r[mrow * C_ + h * 64 + nn]);
        float val = rr * (g * fbuf[tl * 64 + nn] + (1.f - g) * bbuf[tl * 64 + nn]);
        xc[mrow * C_ + h * 64 + nn] = f2bfu(val);
    }
}

// =====================================================================
// 256x256 8-phase bf16 GEMM (T2 swizzle + T3/T4 counted vmcnt + T5 setprio)
// C[M,N] = A[M,K] * B[N,K]^T. 8 waves (2m x 4n), BK=64, 128KiB LDS dbuf.
// Per wave: 128x64 output = acc[8][4] f32x4.
// LDS swizzle: byte ^= (row&7)<<4 on reads; staging uses linear LDS dest
// (global_load_lds) + inverse-swizzled per-lane GLOBAL source.
// vmcnt(4) once per K-tile, never 0 in the loop. Raw s_barrier (no drain).
// SHIFT: A row m reads row m-1 (t==0 rows -> zero page).
// EPI: 0 bf16; 1 f32; 2 f32 extra+acc; 3 relu^2 bf16
// =====================================================================
#define LDS_FENCE() asm volatile("" ::: "memory")
#define PHASE_BAR() do { __builtin_amdgcn_sched_barrier(0); LDS_FENCE(); \
                         __builtin_amdgcn_s_barrier(); \
                         LDS_FENCE(); __builtin_amdgcn_sched_barrier(0); } while (0)
#define SETP(x) __builtin_amdgcn_s_setprio(x)

template <int EPI, bool SHIFT>
__global__ __launch_bounds__(512, 2) void gemm256(const ushort_t* __restrict__ A,
                                                  const ushort_t* __restrict__ Bm,
                                                  const float* __restrict__ extra,
                                                  float* __restrict__ outF,
                                                  ushort_t* __restrict__ outB,
                                                  const ushort_t* __restrict__ zpage,
                                                  int N, int K) {
    __shared__ ushort_t As[2][256 * 64];   // 64 KB
    __shared__ ushort_t Bs[2][256 * 64];   // 64 KB
    const int NT = K >> 6;                 // K-tiles (even, >=2 for all our shapes)
    const int tid = threadIdx.x;
    const int lane = tid & 63, wv = tid >> 6;
    const int wm = wv >> 2, wn = wv & 3;   // 2 x 4 wave grid
    const size_t m0 = (size_t)(blockIdx.x & 63) * 256;   // Mtiles = 64 always
    const size_t n0 = (size_t)(blockIdx.x >> 6) * 256;

    // ---- staging: per-lane pre-swizzled global sources ----
    // issue covers 8 rows x 64 cols; lane l -> row l>>3, phys chunk l&7;
    // logical chunk = (l&7) ^ (l>>3)  (inverse of read-side byte^=(row&7)<<4)
    const int l8 = lane >> 3;
    const int swcol = ((lane & 7) ^ l8) * 8;   // elements
    const ushort_t* pA[2][2];
    const ushort_t* pB[2][2];
#pragma unroll
    for (int hf = 0; hf < 2; ++hf)
#pragma unroll
        for (int i8 = 0; i8 < 2; ++i8) {
            const size_t tr = (size_t)(hf * 128 + wv * 16 + i8 * 8 + l8);
            const size_t mrow = m0 + tr, nrow = n0 + tr;
            if (SHIFT)
                pA[hf][i8] = ((mrow & (size_t)(T_ - 1)) == 0)
                                 ? (zpage + swcol)
                                 : (A + (mrow - 1) * (size_t)K + swcol);
            else
                pA[hf][i8] = A + mrow * (size_t)K + swcol;
            pB[hf][i8] = Bm + nrow * (size_t)K + swcol;
        }

    // ---- swizzled fragment-read offsets ----
    const int rl = lane & 15;
    const int swz = (lane & 7) << 4;           // (row&7)<<4, row = R0+rl, R0%16==0
    const int cq = (lane >> 4) << 4;           // (lane>>4)*16 bytes
    const int offk0 = cq ^ swz;                // kk=0
    const int offk1 = (64 | cq) ^ swz;         // kk=1 (+32 elements)
    const int aRow = (wm * 128 + rl) * 128;    // byte offset of frag row, mi=0,qm=0
    const int bRow = (wn * 64 + rl) * 128;

    bf16x8 a[8], b[8];
    f32x4 acc[8][4];
#pragma unroll
    for (int i = 0; i < 8; ++i)
#pragma unroll
        for (int j = 0; j < 4; ++j) acc[i][j] = (f32x4){0.f, 0.f, 0.f, 0.f};

#define STAGE_A(BUF, HF, KOF) do { \
    gl_lds16(pA[HF][0] + (KOF), &As[BUF][((HF) * 128 + wv * 16 + 0) * 64]); \
    gl_lds16(pA[HF][1] + (KOF), &As[BUF][((HF) * 128 + wv * 16 + 8) * 64]); } while (0)
#define STAGE_B(BUF, HF, KOF) do { \
    gl_lds16(pB[HF][0] + (KOF), &Bs[BUF][((HF) * 128 + wv * 16 + 0) * 64]); \
    gl_lds16(pB[HF][1] + (KOF), &Bs[BUF][((HF) * 128 + wv * 16 + 8) * 64]); } while (0)
#define LOAD_A(BUF, QM) do { \
    const char* _ab = (const char*)As[BUF] + aRow + (QM) * 64 * 128; \
    _Pragma("unroll") \
    for (int mi = 0; mi < 4; ++mi) { \
        a[mi * 2 + 0] = *(const bf16x8*)(_ab + mi * 16 * 128 + offk0); \
        a[mi * 2 + 1] = *(const bf16x8*)(_ab + mi * 16 * 128 + offk1); } } while (0)
#define LOAD_B(BUF, QN) do { \
    const char* _bb = (const char*)Bs[BUF] + bRow + (QN) * 32 * 128; \
    _Pragma("unroll") \
    for (int ni = 0; ni < 2; ++ni) { \
        b[((QN) * 2 + ni) * 2 + 0] = *(const bf16x8*)(_bb + ni * 16 * 128 + offk0); \
        b[((QN) * 2 + ni) * 2 + 1] = *(const bf16x8*)(_bb + ni * 16 * 128 + offk1); } } while (0)
#define MFMA_Q(QM, QN) do { \
    _Pragma("unroll") \
    for (int mi = 0; mi < 4; ++mi) \
    _Pragma("unroll") \
    for (int ni = 0; ni < 2; ++ni) { \
        acc[(QM)*4+mi][(QN)*2+ni] = __builtin_amdgcn_mfma_f32_16x16x32_bf16( \
            a[mi*2+0], b[((QN)*2+ni)*2+0], acc[(QM)*4+mi][(QN)*2+ni], 0, 0, 0); \
        acc[(QM)*4+mi][(QN)*2+ni] = __builtin_amdgcn_mfma_f32_16x16x32_bf16( \
            a[mi*2+1], b[((QN)*2+ni)*2+1], acc[(QM)*4+mi][(QN)*2+ni], 0, 0, 0); } } while (0)

// One K-tile = 4 phases. CB = compute buffer, OB = other buffer.
// p0: read A-own-qm0(8) + B-own-qn0(4); stage A0(k+1)->OB  | MFMA Q(0,0)
// p1: read B-own-qn1(4);               stage A1(k+1)->OB  | MFMA Q(0,1)
// p2: read A-own-qm1(8);               stage B0(k+2)->CB  | MFMA Q(1,1)
// p3:                                  stage B1(k+2)->CB  | MFMA Q(1,0); vmcnt(4)
// Region-closure: B(CB) last read p1, restaged p2/p3; A(OB) closed prev tile.
// vmcnt(4) leaves {B0,B1(k+2)} in flight, guarantees A(k+1) landed.
#define KTILE(CB, OB, KT) do { \
    const int _kA = ((KT) + 1 < NT) ? ((KT) + 1) * 64 : 0; \
    const int _kB = ((KT) + 2 < NT) ? ((KT) + 2) * 64 : 0; \
    LOAD_A(CB, 0); LOAD_B(CB, 0); STAGE_A(OB, 0, _kA); \
    PHASE_BAR(); SETP(1); MFMA_Q(0, 0); SETP(0); PHASE_BAR(); \
    LOAD_B(CB, 1); STAGE_A(OB, 1, _kA); \
    PHASE_BAR(); SETP(1); MFMA_Q(0, 1); SETP(0); PHASE_BAR(); \
    LOAD_A(CB, 1); STAGE_B(CB, 0, _kB); \
    PHASE_BAR(); SETP(1); MFMA_Q(1, 1); SETP(0); PHASE_BAR(); \
    STAGE_B(CB, 1, _kB); \
    PHASE_BAR(); SETP(1); MFMA_Q(1, 0); SETP(0); \
    asm volatile("s_waitcnt vmcnt(4)" ::: "memory"); \
    PHASE_BAR(); } while (0)

    // prologue: B(t0), A(t0), B(t1); A(t1) is staged inside tile 0's p0/p1
    STAGE_B(0, 0, 0); STAGE_B(0, 1, 0);
    STAGE_A(0, 0, 0); STAGE_A(0, 1, 0);
    const int _k1 = 64;
    STAGE_B(1, 0, _k1); STAGE_B(1, 1, _k1);
    asm volatile("s_waitcnt vmcnt(4)" ::: "memory");   // t0 fully landed
    PHASE_BAR();

    for (int kt = 0; kt < NT; kt += 2) {
        KTILE(0, 1, kt);
        KTILE(1, 0, kt + 1);
    }

#undef KTILE
#undef MFMA_Q
#undef LOAD_B
#undef LOAD_A
#undef STAGE_B
#undef STAGE_A

    // epilogue: C/D layout col=lane&15, row=(lane>>4)*4+reg
    const int crow = (lane >> 4) * 4;
    const int ccol = lane & 15;
#pragma unroll
    for (int mi = 0; mi < 8; ++mi) {
#pragma unroll
        for (int ni = 0; ni < 4; ++ni) {
#pragma unroll
            for (int rr = 0; rr < 4; ++rr) {
                size_t row = m0 + wm * 128 + mi * 16 + crow + rr;
                size_t col = n0 + wn * 64 + ni * 16 + ccol;
                size_t oix = row * (size_t)N + col;
                float v = acc[mi][ni][rr];
                if (EPI == 0)      outB[oix] = f2bfu(v);
                else if (EPI == 1) outF[oix] = v;
                else if (EPI == 2) outF[oix] = extra[oix] + v;
                else { float t = v > 0.f ? v : 0.f; outB[oix] = f2bfu(t * t); }
            }
        }
    }
}

// =====================================================================
// launcher
// =====================================================================
extern "C" void kernel_launch(void* const* d_in, const int* in_sizes, int n_in,
                              void* d_out, int out_size, void* d_ws, size_t ws_size,
                              hipStream_t stream) {
    const float* x    = (const float*)d_in[0];
    const float* ln1w = (const float*)d_in[2];
    const float* ln1b = (const float*)d_in[3];
    const float* ln2w = (const float*)d_in[4];
    const float* ln2b = (const float*)d_in[5];
    const float* w_r  = (const float*)d_in[6];
    // d_in[7] = w_k: unused by the reference's _wkv — skipped.
    const float* w_v  = (const float*)d_in[8];
    const float* w_o  = (const float*)d_in[9];
    const float* w_g  = (const float*)d_in[10];
    const float* ck_w = (const float*)d_in[11];
    const float* cv_w = (const float*)d_in[12];

    float* out0 = (float*)d_out;                       // x1 + ffn_out  [M,C]
    float* vout = out0 + (size_t)M_ * C_;              // v_first_out   [M,C] fp32

    char* ws = (char*)d_ws;
    const size_t MB = 1024ull * 1024ull;
    ushort_t* wr_bf = (ushort_t*)(ws + 0 * MB);        // 2MB
    ushort_t* wv_bf = (ushort_t*)(ws + 2 * MB);        // 2MB
    ushort_t* wo_bf = (ushort_t*)(ws + 4 * MB);        // 2MB
    ushort_t* ck_bf = (ushort_t*)(ws + 6 * MB);        // 8MB
    ushort_t* cv_bf = (ushort_t*)(ws + 14 * MB);       // 8MB
    float*    gate  = (float*)(ws + 22 * MB);          // 1MB
    ushort_t* zpage = (ushort_t*)(ws + 23 * MB);       // 16KB (1MB slot)
    ushort_t* bufA  = (ushort_t*)(ws + 24 * MB);       // 32MB  h1, later h2
    ushort_t* bufC  = (ushort_t*)(ws + 56 * MB);       // 32MB  x_comb
    ushort_t* r_bf  = (ushort_t*)(ws + 88 * MB);       // 32MB
    float*    x1    = (float*)(ws + 120 * MB);         // 64MB
    ushort_t* k2p   = (ushort_t*)(ws + 184 * MB);      // 128MB; total 312MB

    // weights fp32 -> bf16; zero page for shifted GEMM rows
    f2bf3_kernel<<<dim3(C_ * C_ / 1024, 3), 256, 0, stream>>>(w_r, w_v, w_o, wr_bf, wv_bf, wo_bf);
    f2bf2_kernel<<<dim3(FC_ * C_ / 1024, 2), 256, 0, stream>>>(ck_w, cv_w, ck_bf, cv_bf);
    hipMemsetAsync(zpage, 0, 16384, stream);

    // h = LN1(x)
    ln_kernel<<<M_, 256, 0, stream>>>(x, ln1w, ln1b, bufA);

    // gate = sigmoid((shift(h)-h) @ w_g^T)
    gate_kernel<<<M_, 256, 0, stream>>>(bufA, w_g, gate);

    // r = shift(h) @ w_r^T (bf16); v = shift(h) @ w_v^T (fp32, = output 1)
    gemm256<0, true><<<(M_ / 256) * (C_ / 256), 512, 0, stream>>>(bufA, wr_bf, nullptr, nullptr, r_bf, zpage, C_, C_);
    gemm256<1, true><<<(M_ / 256) * (C_ / 256), 512, 0, stream>>>(bufA, wv_bf, nullptr, vout, nullptr, zpage, C_, C_);

    // wkv fwd+bwd + combine -> x_comb
    wkv_combine_kernel<<<B_ * H_ * (T_ / 128), 128, 0, stream>>>(vout, r_bf, gate, bufC);

    // x1 = x + x_comb @ w_o^T
    gemm256<2, false><<<(M_ / 256) * (C_ / 256), 512, 0, stream>>>(bufC, wo_bf, x, x1, nullptr, zpage, C_, C_);

    // h2 = LN2(x1)
    ln_kernel<<<M_, 256, 0, stream>>>(x1, ln2w, ln2b, bufA);

    // k2p = relu(shift(h2) @ ck_w^T)^2; out0 = x1 + k2p @ cv_w^T
    gemm256<3, true><<<(M_ / 256) * (FC_ / 256), 512, 0, stream>>>(bufA, ck_bf, nullptr, nullptr, k2p, zpage, FC_, C_);
    gemm256<2, false><<<(M_ / 256) * (C_ / 256), 512, 0, stream>>>(k2p, cv_bf, x1, out0, nullptr, zpage, C_, FC_);
}

// Round 2
// 844.631 us; speedup vs baseline: 1.0703x; 1.0431x over previous
//
#include <hip/hip_runtime.h>

// ---- problem constants ----
constexpr int B_ = 8, T_ = 2048, C_ = 1024, H_ = 16, N_ = 64;
constexpr int M_ = B_ * T_;              // 16384 rows
constexpr int FC_ = 4 * C_;              // 4096

typedef __attribute__((ext_vector_type(8))) short bf16x8;
typedef __attribute__((ext_vector_type(4))) float f32x4;
typedef unsigned short ushort_t;
typedef unsigned int uint_t;

__device__ __forceinline__ float bfu2f(ushort_t u) {
    union { uint_t i; float f; } c; c.i = ((uint_t)u) << 16; return c.f;
}
__device__ __forceinline__ ushort_t f2bfu(float f) {
    union { float f; uint_t i; } c; c.f = f;
    uint_t i = c.i;
    uint_t r = i + 0x7FFFu + ((i >> 16) & 1u);   // round-to-nearest-even
    return (ushort_t)(r >> 16);
}

__device__ __forceinline__ void gl_lds16(const void* g, void* l) {
    __builtin_amdgcn_global_load_lds(
        (const __attribute__((address_space(1))) void*)g,
        (__attribute__((address_space(3))) void*)l, 16, 0, 0);
}

// =====================================================================
// fp32 -> bf16 weight converts, folded into 2 launches
// =====================================================================
__global__ __launch_bounds__(256) void f2bf3_kernel(const float* __restrict__ a,
                                                    const float* __restrict__ b,
                                                    const float* __restrict__ c,
                                                    ushort_t* __restrict__ oa,
                                                    ushort_t* __restrict__ ob,
                                                    ushort_t* __restrict__ oc) {
    const float* in = (blockIdx.y == 0) ? a : (blockIdx.y == 1) ? b : c;
    ushort_t* out   = (blockIdx.y == 0) ? oa : (blockIdx.y == 1) ? ob : oc;
    size_t i = ((size_t)blockIdx.x * 256 + threadIdx.x) * 4;
    float4 v = *(const float4*)(in + i);
    uint2 o;
    o.x = (uint_t)f2bfu(v.x) | ((uint_t)f2bfu(v.y) << 16);
    o.y = (uint_t)f2bfu(v.z) | ((uint_t)f2bfu(v.w) << 16);
    *(uint2*)(out + i) = o;
}

__global__ __launch_bounds__(256) void f2bf2_kernel(const float* __restrict__ a,
                                                    const float* __restrict__ b,
                                                    ushort_t* __restrict__ oa,
                                                    ushort_t* __restrict__ ob) {
    const float* in = (blockIdx.y == 0) ? a : b;
    ushort_t* out   = (blockIdx.y == 0) ? oa : ob;
    size_t i = ((size_t)blockIdx.x * 256 + threadIdx.x) * 4;
    float4 v = *(const float4*)(in + i);
    uint2 o;
    o.x = (uint_t)f2bfu(v.x) | ((uint_t)f2bfu(v.y) << 16);
    o.y = (uint_t)f2bfu(v.z) | ((uint_t)f2bfu(v.w) << 16);
    *(uint2*)(out + i) = o;
}

// =====================================================================
// LayerNorm over C=1024, one block per row, output bf16
// =====================================================================
__global__ __launch_bounds__(256) void ln_kernel(const float* __restrict__ x,
                                                 const float* __restrict__ w,
                                                 const float* __restrict__ b,
                                                 ushort_t* __restrict__ out) {
    const int row = blockIdx.x;
    const int tid = threadIdx.x;
    const float* xr = x + (size_t)row * C_;
    float4 xv = ((const float4*)xr)[tid];
    float s  = xv.x + xv.y + xv.z + xv.w;
    float ss = xv.x*xv.x + xv.y*xv.y + xv.z*xv.z + xv.w*xv.w;
#pragma unroll
    for (int off = 32; off; off >>= 1) { s += __shfl_down(s, off); ss += __shfl_down(ss, off); }
    __shared__ float sb[8];
    const int wv = tid >> 6, ln = tid & 63;
    if (ln == 0) { sb[wv] = s; sb[4 + wv] = ss; }
    __syncthreads();
    s  = sb[0] + sb[1] + sb[2] + sb[3];
    ss = sb[4] + sb[5] + sb[6] + sb[7];
    const float mean = s * (1.f / C_);
    const float var  = ss * (1.f / C_) - mean * mean;
    const float rstd = rsqrtf(var + 1e-5f);
    float4 wv4 = ((const float4*)w)[tid];
    float4 bv4 = ((const float4*)b)[tid];
    uint2 o;
    o.x = (uint_t)f2bfu((xv.x - mean) * rstd * wv4.x + bv4.x)
        | ((uint_t)f2bfu((xv.y - mean) * rstd * wv4.y + bv4.y) << 16);
    o.y = (uint_t)f2bfu((xv.z - mean) * rstd * wv4.z + bv4.z)
        | ((uint_t)f2bfu((xv.w - mean) * rstd * wv4.w + bv4.w) << 16);
    ((uint2*)(out + (size_t)row * C_))[tid] = o;
}

// =====================================================================
// gate[m,h] = sigmoid(dot(xx[m,:], w_g[h,:])), xx computed inline
// =====================================================================
__global__ __launch_bounds__(256) void gate_kernel(const ushort_t* __restrict__ h,
                                                   const float* __restrict__ wg,
                                                   float* __restrict__ gate) {
    __shared__ float xr[C_];
    const int row = blockIdx.x;
    const int tid = threadIdx.x;
    const int t = row & (T_ - 1);
    uint2 cu = *(const uint2*)(h + (size_t)row * C_ + tid * 4);
    uint2 pu = make_uint2(0u, 0u);
    if (t > 0) pu = *(const uint2*)(h + (size_t)(row - 1) * C_ + tid * 4);
    xr[tid * 4 + 0] = bfu2f((ushort_t)(pu.x & 0xffffu)) - bfu2f((ushort_t)(cu.x & 0xffffu));
    xr[tid * 4 + 1] = bfu2f((ushort_t)(pu.x >> 16))     - bfu2f((ushort_t)(cu.x >> 16));
    xr[tid * 4 + 2] = bfu2f((ushort_t)(pu.y & 0xffffu)) - bfu2f((ushort_t)(cu.y & 0xffffu));
    xr[tid * 4 + 3] = bfu2f((ushort_t)(pu.y >> 16))     - bfu2f((ushort_t)(cu.y >> 16));
    __syncthreads();
    const int wv = tid >> 6, ln = tid & 63;
#pragma unroll
    for (int hh = 0; hh < 4; ++hh) {
        const int h_ = wv * 4 + hh;
        const float* wrow = wg + (size_t)h_ * C_;
        float acc = 0.f;
#pragma unroll
        for (int i = 0; i < 16; ++i) { int c = i * 64 + ln; acc += xr[c] * wrow[c]; }
#pragma unroll
        for (int off = 32; off; off >>= 1) acc += __shfl_down(acc, off);
        if (ln == 0) gate[(size_t)row * H_ + h_] = 1.f / (1.f + __expf(-acc));
    }
}

// =====================================================================
// wkv fwd+bwd scan (decay 0.5) with 32-step warmup windows, fused combine
// =====================================================================
__global__ __launch_bounds__(128) void wkv_combine_kernel(const float* __restrict__ v,
                                                          const ushort_t* __restrict__ r,
                                                          const float* __restrict__ gate,
                                                          ushort_t* __restrict__ xc) {
    __shared__ float fbuf[128 * 64];
    __shared__ float bbuf[128 * 64];
    const int blk = blockIdx.x;           // b*256 + h*16 + chunk
    const int chunk = blk & 15;
    const int bh = blk >> 4;
    const int h = bh & 15;
    const int b = bh >> 4;
    const int t0 = chunk * 128, t1 = t0 + 128;
    const int tid = threadIdx.x;
    const int n = tid & 63;
    const float* vb = v + (size_t)b * T_ * C_ + h * 64 + n;
    if (tid < 64) {                       // wave 0: forward
        int ts = t0 - 32; if (ts < 0) ts = 0;
        float carry = vb[(size_t)ts * C_];
        if (ts >= t0) fbuf[(ts - t0) * 64 + n] = carry;
        for (int t = ts + 1; t < t1; ++t) {
            carry = 0.5f * (carry + vb[(size_t)t * C_]);
            if (t >= t0) fbuf[(t - t0) * 64 + n] = carry;
        }
    } else {                              // wave 1: backward
        int ts = t1 - 1 + 32; if (ts > T_ - 1) ts = T_ - 1;
        float carry = vb[(size_t)ts * C_];
        if (ts < t1) bbuf[(ts - t0) * 64 + n] = carry;
        for (int t = ts - 1; t >= t0; --t) {
            carry = 0.5f * (carry + vb[(size_t)t * C_]);
            if (t < t1) bbuf[(t - t0) * 64 + n] = carry;
        }
    }
    __syncthreads();
#pragma unroll 4
    for (int i = 0; i < 64; ++i) {
        int idx = i * 128 + tid;
        int tl = idx >> 6, nn = idx & 63;
        size_t mrow = (size_t)b * T_ + (t0 + tl);
        float g = gate[mrow * H_ + h];
        float rr = bfu2f(r[mrow * C_ + h * 64 + nn]);
        float val = rr * (g * fbuf[tl * 64 + nn] + (1.f - g) * bbuf[tl * 64 + nn]);
        xc[mrow * C_ + h * 64 + nn] = f2bfu(val);
    }
}

// =====================================================================
// 256x256 pipelined bf16 GEMM. C[M,N] = A[M,K] * B[N,K]^T.
// 8 waves (2m x 4n), BK=64, 128KiB LDS dbuf, per wave 128x64 = acc[8][4].
// Register-fragment pipeline: every MFMA's ds_reads issue >=1 phase before
// use -> compiler emits counted lgkmcnt -> LDS latency hides under MFMA.
// One s_barrier per phase (4/tile). Counted vmcnt(4)/vmcnt(2), never 0.
// LDS swizzle: byte ^= (row&7)<<4 on reads; linear LDS dest + inverse-
// swizzled per-lane GLOBAL source for global_load_lds.
// Quadrant order Q00,Q01,Q10,Q11; post-MFMA reads reuse freed fragment regs
// (a[] shared between qm halves, b0/b1 separate) -> 64 frag VGPRs, no spill.
// SHIFT: A row m reads row m-1 (t==0 rows -> zero page).
// EPI: 0 bf16; 1 f32; 2 f32 extra+acc; 3 relu^2 bf16
// =====================================================================
#define BAR() do { asm volatile("" ::: "memory"); \
                   __builtin_amdgcn_s_barrier(); \
                   asm volatile("" ::: "memory"); } while (0)
#define SETP(x) __builtin_amdgcn_s_setprio(x)
#define SCHEDB() __builtin_amdgcn_sched_barrier(0)
#define VMCNT(n) asm volatile("s_waitcnt vmcnt(" #n ")" ::: "memory")

template <int EPI, bool SHIFT>
__global__ __launch_bounds__(512, 2) void gemm256(const ushort_t* __restrict__ A,
                                                  const ushort_t* __restrict__ Bm,
                                                  const float* __restrict__ extra,
                                                  float* __restrict__ outF,
                                                  ushort_t* __restrict__ outB,
                                                  const ushort_t* __restrict__ zpage,
                                                  int N, int K) {
    __shared__ ushort_t As[2][256 * 64];   // 64 KB
    __shared__ ushort_t Bs[2][256 * 64];   // 64 KB
    const int NT = K >> 6;                 // K-tiles (even >=2 for all shapes here)
    const int tid = threadIdx.x;
    const int lane = tid & 63, wv = tid >> 6;
    const int wm = wv >> 2, wn = wv & 3;   // 2 x 4 wave grid
    const size_t m0 = (size_t)(blockIdx.x & 63) * 256;   // Mtiles = 64 always
    const size_t n0 = (size_t)(blockIdx.x >> 6) * 256;

    // ---- staging: per-lane pre-swizzled global sources ----
    // issue covers 8 rows x 64 cols; lane l -> row l>>3, phys chunk l&7;
    // logical chunk = (l&7) ^ (l>>3)  (inverse of read-side byte^=(row&7)<<4)
    const int l8 = lane >> 3;
    const int swcol = ((lane & 7) ^ l8) * 8;   // elements
    const ushort_t* pA[2][2];
    const ushort_t* pB[2][2];
#pragma unroll
    for (int hf = 0; hf < 2; ++hf)
#pragma unroll
        for (int i8 = 0; i8 < 2; ++i8) {
            const size_t tr = (size_t)(hf * 128 + wv * 16 + i8 * 8 + l8);
            const size_t mrow = m0 + tr, nrow = n0 + tr;
            if (SHIFT)
                pA[hf][i8] = ((mrow & (size_t)(T_ - 1)) == 0)
                                 ? (zpage + swcol)
                                 : (A + (mrow - 1) * (size_t)K + swcol);
            else
                pA[hf][i8] = A + mrow * (size_t)K + swcol;
            pB[hf][i8] = Bm + nrow * (size_t)K + swcol;
        }

    // ---- swizzled fragment-read offsets ----
    const int rl = lane & 15;
    const int swz = (lane & 7) << 4;           // (row&7)<<4, row = R0+rl, R0%16==0
    const int cq = (lane >> 4) << 4;           // (lane>>4)*16 bytes
    const int offk0 = cq ^ swz;                // kk=0
    const int offk1 = (64 | cq) ^ swz;         // kk=1 (+32 elements)
    const int aRow = (wm * 128 + rl) * 128;    // byte offset of frag row, mi=0,qm=0
    const int bRow = (wn * 64 + rl) * 128;

    bf16x8 a[8], b0[4], b1[4];
    f32x4 acc[8][4];
#pragma unroll
    for (int i = 0; i < 8; ++i)
#pragma unroll
        for (int j = 0; j < 4; ++j) acc[i][j] = (f32x4){0.f, 0.f, 0.f, 0.f};

#define STAGE_A(BUF, HF, KOF) do { \
    gl_lds16(pA[HF][0] + (KOF), &As[BUF][((HF) * 128 + wv * 16 + 0) * 64]); \
    gl_lds16(pA[HF][1] + (KOF), &As[BUF][((HF) * 128 + wv * 16 + 8) * 64]); } while (0)
#define STAGE_B(BUF, HF, KOF) do { \
    gl_lds16(pB[HF][0] + (KOF), &Bs[BUF][((HF) * 128 + wv * 16 + 0) * 64]); \
    gl_lds16(pB[HF][1] + (KOF), &Bs[BUF][((HF) * 128 + wv * 16 + 8) * 64]); } while (0)
#define LOAD_A(ARR, BUF, QM) do { \
    const char* _ab = (const char*)As[BUF] + aRow + (QM) * 64 * 128; \
    _Pragma("unroll") \
    for (int mi = 0; mi < 4; ++mi) { \
        ARR[mi * 2 + 0] = *(const bf16x8*)(_ab + mi * 16 * 128 + offk0); \
        ARR[mi * 2 + 1] = *(const bf16x8*)(_ab + mi * 16 * 128 + offk1); } } while (0)
#define LOAD_B(ARR, BUF, QN) do { \
    const char* _bb = (const char*)Bs[BUF] + bRow + (QN) * 32 * 128; \
    _Pragma("unroll") \
    for (int ni = 0; ni < 2; ++ni) { \
        ARR[ni * 2 + 0] = *(const bf16x8*)(_bb + ni * 16 * 128 + offk0); \
        ARR[ni * 2 + 1] = *(const bf16x8*)(_bb + ni * 16 * 128 + offk1); } } while (0)
#define MFMA_Q(AARR, BARR, QM, QN) do { \
    _Pragma("unroll") \
    for (int mi = 0; mi < 4; ++mi) \
    _Pragma("unroll") \
    for (int ni = 0; ni < 2; ++ni) { \
        acc[(QM)*4+mi][(QN)*2+ni] = __builtin_amdgcn_mfma_f32_16x16x32_bf16( \
            AARR[mi*2+0], BARR[ni*2+0], acc[(QM)*4+mi][(QN)*2+ni], 0, 0, 0); \
        acc[(QM)*4+mi][(QN)*2+ni] = __builtin_amdgcn_mfma_f32_16x16x32_bf16( \
            AARR[mi*2+1], BARR[ni*2+1], acc[(QM)*4+mi][(QN)*2+ni], 0, 0, 0); } } while (0)

// Per-tile (CB=t&1). Entering: a[]=a0(t), b0[]=b0(t) (read in prev P3 / prologue).
// P0: rd b1(t);            st A0(t+1)->OB; MFMA Q00(a0,b0)
// P1:                      st A1(t+1)->OB; MFMA Q01(a0,b1); rd a1(t); vmcnt(4)
// P2:                      st B0(t+2)->CB; MFMA Q10(a1,b0); vmcnt(2)
// P3: rd b0(t+1)<-OB;      st B1(t+2)->CB; MFMA Q11(a1,b1); rd a0(t+1)<-OB
// vmcnt(4)@P1 drains B(t+1) (staged t-1 P2/P3) before its P3 read;
// vmcnt(2)@P2 drains A(t+1) (staged t P0/P1) before its P3 read;
// cross-wave visibility via the barrier that follows each vmcnt.
#define KTILE(CB, OB, KT) do { \
    const int _kA = ((KT) + 1 < NT) ? ((KT) + 1) * 64 : 0; \
    const int _kB = ((KT) + 2 < NT) ? ((KT) + 2) * 64 : 0; \
    BAR(); \
    LOAD_B(b1, CB, 1); \
    STAGE_A(OB, 0, _kA); \
    SETP(1); MFMA_Q(a, b0, 0, 0); SETP(0); \
    BAR(); \
    STAGE_A(OB, 1, _kA); \
    SETP(1); MFMA_Q(a, b1, 0, 1); SETP(0); \
    SCHEDB(); \
    LOAD_A(a, CB, 1); \
    VMCNT(4); \
    BAR(); \
    STAGE_B(CB, 0, _kB); \
    SETP(1); MFMA_Q(a, b0, 1, 0); SETP(0); \
    VMCNT(2); \
    BAR(); \
    LOAD_B(b0, OB, 0); \
    STAGE_B(CB, 1, _kB); \
    SETP(1); MFMA_Q(a, b1, 1, 1); SETP(0); \
    SCHEDB(); \
    LOAD_A(a, OB, 0); \
  } while (0)

    // prologue: stage A(0),B(0),B(1); drain A(0),B(0) (leave B(1) in flight);
    // pre-read tile-0 fragments a0,b0.
    STAGE_A(0, 0, 0); STAGE_A(0, 1, 0);
    STAGE_B(0, 0, 0); STAGE_B(0, 1, 0);
    const int _k1 = (NT > 1) ? 64 : 0;
    STAGE_B(1, 0, _k1); STAGE_B(1, 1, _k1);
    VMCNT(4);
    BAR();
    LOAD_A(a, 0, 0);
    LOAD_B(b0, 0, 0);

    for (int kt = 0; kt < NT; kt += 2) {
        KTILE(0, 1, kt);
        KTILE(1, 0, kt + 1);
    }

#undef KTILE
#undef MFMA_Q
#undef LOAD_B
#undef LOAD_A
#undef STAGE_B
#undef STAGE_A

    // epilogue: C/D layout col=lane&15, row=(lane>>4)*4+reg
    const int crow = (lane >> 4) * 4;
    const int ccol = lane & 15;
#pragma unroll
    for (int mi = 0; mi < 8; ++mi) {
#pragma unroll
        for (int ni = 0; ni < 4; ++ni) {
#pragma unroll
            for (int rr = 0; rr < 4; ++rr) {
                size_t row = m0 + wm * 128 + mi * 16 + crow + rr;
                size_t col = n0 + wn * 64 + ni * 16 + ccol;
                size_t oix = row * (size_t)N + col;
                float v = acc[mi][ni][rr];
                if (EPI == 0)      outB[oix] = f2bfu(v);
                else if (EPI == 1) outF[oix] = v;
                else if (EPI == 2) outF[oix] = extra[oix] + v;
                else { float t = v > 0.f ? v : 0.f; outB[oix] = f2bfu(t * t); }
            }
        }
    }
}

// =====================================================================
// launcher
// =====================================================================
extern "C" void kernel_launch(void* const* d_in, const int* in_sizes, int n_in,
                              void* d_out, int out_size, void* d_ws, size_t ws_size,
                              hipStream_t stream) {
    const float* x    = (const float*)d_in[0];
    const float* ln1w = (const float*)d_in[2];
    const float* ln1b = (const float*)d_in[3];
    const float* ln2w = (const float*)d_in[4];
    const float* ln2b = (const float*)d_in[5];
    const float* w_r  = (const float*)d_in[6];
    // d_in[7] = w_k: unused by the reference's _wkv — skipped.
    const float* w_v  = (const float*)d_in[8];
    const float* w_o  = (const float*)d_in[9];
    const float* w_g  = (const float*)d_in[10];
    const float* ck_w = (const float*)d_in[11];
    const float* cv_w = (const float*)d_in[12];

    float* out0 = (float*)d_out;                       // x1 + ffn_out  [M,C]
    float* vout = out0 + (size_t)M_ * C_;              // v_first_out   [M,C] fp32

    char* ws = (char*)d_ws;
    const size_t MB = 1024ull * 1024ull;
    ushort_t* wr_bf = (ushort_t*)(ws + 0 * MB);        // 2MB
    ushort_t* wv_bf = (ushort_t*)(ws + 2 * MB);        // 2MB
    ushort_t* wo_bf = (ushort_t*)(ws + 4 * MB);        // 2MB
    ushort_t* ck_bf = (ushort_t*)(ws + 6 * MB);        // 8MB
    ushort_t* cv_bf = (ushort_t*)(ws + 14 * MB);       // 8MB
    float*    gate  = (float*)(ws + 22 * MB);          // 1MB
    ushort_t* zpage = (ushort_t*)(ws + 23 * MB);       // 16KB (1MB slot)
    ushort_t* bufA  = (ushort_t*)(ws + 24 * MB);       // 32MB  h1, later h2
    ushort_t* bufC  = (ushort_t*)(ws + 56 * MB);       // 32MB  x_comb
    ushort_t* r_bf  = (ushort_t*)(ws + 88 * MB);       // 32MB
    float*    x1    = (float*)(ws + 120 * MB);         // 64MB
    ushort_t* k2p   = (ushort_t*)(ws + 184 * MB);      // 128MB; total 312MB

    // weights fp32 -> bf16; zero page for shifted GEMM rows
    f2bf3_kernel<<<dim3(C_ * C_ / 1024, 3), 256, 0, stream>>>(w_r, w_v, w_o, wr_bf, wv_bf, wo_bf);
    f2bf2_kernel<<<dim3(FC_ * C_ / 1024, 2), 256, 0, stream>>>(ck_w, cv_w, ck_bf, cv_bf);
    hipMemsetAsync(zpage, 0, 16384, stream);

    // h = LN1(x)
    ln_kernel<<<M_, 256, 0, stream>>>(x, ln1w, ln1b, bufA);

    // gate = sigmoid((shift(h)-h) @ w_g^T)
    gate_kernel<<<M_, 256, 0, stream>>>(bufA, w_g, gate);

    // r = shift(h) @ w_r^T (bf16); v = shift(h) @ w_v^T (fp32, = output 1)
    gemm256<0, true><<<(M_ / 256) * (C_ / 256), 512, 0, stream>>>(bufA, wr_bf, nullptr, nullptr, r_bf, zpage, C_, C_);
    gemm256<1, true><<<(M_ / 256) * (C_ / 256), 512, 0, stream>>>(bufA, wv_bf, nullptr, vout, nullptr, zpage, C_, C_);

    // wkv fwd+bwd + combine -> x_comb
    wkv_combine_kernel<<<B_ * H_ * (T_ / 128), 128, 0, stream>>>(vout, r_bf, gate, bufC);

    // x1 = x + x_comb @ w_o^T
    gemm256<2, false><<<(M_ / 256) * (C_ / 256), 512, 0, stream>>>(bufC, wo_bf, x, x1, nullptr, zpage, C_, C_);

    // h2 = LN2(x1)
    ln_kernel<<<M_, 256, 0, stream>>>(x1, ln2w, ln2b, bufA);

    // k2p = relu(shift(h2) @ ck_w^T)^2; out0 = x1 + k2p @ cv_w^T
    gemm256<3, true><<<(M_ / 256) * (FC_ / 256), 512, 0, stream>>>(bufA, ck_bf, nullptr, nullptr, k2p, zpage, FC_, C_);
    gemm256<2, false><<<(M_ / 256) * (C_ / 256), 512, 0, stream>>>(k2p, cv_bf, x1, out0, nullptr, zpage, C_, FC_);
}

// Round 3
// 740.824 us; speedup vs baseline: 1.2203x; 1.1401x over previous
//
#include <hip/hip_runtime.h>

// ---- problem constants ----
constexpr int B_ = 8, T_ = 2048, C_ = 1024, H_ = 16, N_ = 64;
constexpr int M_ = B_ * T_;              // 16384 rows
constexpr int FC_ = 4 * C_;              // 4096

typedef __attribute__((ext_vector_type(8))) short bf16x8;
typedef __attribute__((ext_vector_type(4))) float f32x4;
typedef unsigned short ushort_t;
typedef unsigned int uint_t;

__device__ __forceinline__ float bfu2f(ushort_t u) {
    union { uint_t i; float f; } c; c.i = ((uint_t)u) << 16; return c.f;
}
__device__ __forceinline__ ushort_t f2bfu(float f) {
    union { float f; uint_t i; } c; c.f = f;
    uint_t i = c.i;
    uint_t r = i + 0x7FFFu + ((i >> 16) & 1u);   // round-to-nearest-even
    return (ushort_t)(r >> 16);
}

__device__ __forceinline__ void gl_lds16(const void* g, void* l) {
    __builtin_amdgcn_global_load_lds(
        (const __attribute__((address_space(1))) void*)g,
        (__attribute__((address_space(3))) void*)l, 16, 0, 0);
}

// =====================================================================
// fp32 -> bf16 weight converts, folded into 2 launches
// =====================================================================
__global__ __launch_bounds__(256) void f2bf3_kernel(const float* __restrict__ a,
                                                    const float* __restrict__ b,
                                                    const float* __restrict__ c,
                                                    ushort_t* __restrict__ oa,
                                                    ushort_t* __restrict__ ob,
                                                    ushort_t* __restrict__ oc) {
    const float* in = (blockIdx.y == 0) ? a : (blockIdx.y == 1) ? b : c;
    ushort_t* out   = (blockIdx.y == 0) ? oa : (blockIdx.y == 1) ? ob : oc;
    size_t i = ((size_t)blockIdx.x * 256 + threadIdx.x) * 4;
    float4 v = *(const float4*)(in + i);
    uint2 o;
    o.x = (uint_t)f2bfu(v.x) | ((uint_t)f2bfu(v.y) << 16);
    o.y = (uint_t)f2bfu(v.z) | ((uint_t)f2bfu(v.w) << 16);
    *(uint2*)(out + i) = o;
}

__global__ __launch_bounds__(256) void f2bf2_kernel(const float* __restrict__ a,
                                                    const float* __restrict__ b,
                                                    ushort_t* __restrict__ oa,
                                                    ushort_t* __restrict__ ob) {
    const float* in = (blockIdx.y == 0) ? a : b;
    ushort_t* out   = (blockIdx.y == 0) ? oa : ob;
    size_t i = ((size_t)blockIdx.x * 256 + threadIdx.x) * 4;
    float4 v = *(const float4*)(in + i);
    uint2 o;
    o.x = (uint_t)f2bfu(v.x) | ((uint_t)f2bfu(v.y) << 16);
    o.y = (uint_t)f2bfu(v.z) | ((uint_t)f2bfu(v.w) << 16);
    *(uint2*)(out + i) = o;
}

// =====================================================================
// LayerNorm over C=1024, one block per row, output bf16
// =====================================================================
__global__ __launch_bounds__(256) void ln_kernel(const float* __restrict__ x,
                                                 const float* __restrict__ w,
                                                 const float* __restrict__ b,
                                                 ushort_t* __restrict__ out) {
    const int row = blockIdx.x;
    const int tid = threadIdx.x;
    const float* xr = x + (size_t)row * C_;
    float4 xv = ((const float4*)xr)[tid];
    float s  = xv.x + xv.y + xv.z + xv.w;
    float ss = xv.x*xv.x + xv.y*xv.y + xv.z*xv.z + xv.w*xv.w;
#pragma unroll
    for (int off = 32; off; off >>= 1) { s += __shfl_down(s, off); ss += __shfl_down(ss, off); }
    __shared__ float sb[8];
    const int wv = tid >> 6, ln = tid & 63;
    if (ln == 0) { sb[wv] = s; sb[4 + wv] = ss; }
    __syncthreads();
    s  = sb[0] + sb[1] + sb[2] + sb[3];
    ss = sb[4] + sb[5] + sb[6] + sb[7];
    const float mean = s * (1.f / C_);
    const float var  = ss * (1.f / C_) - mean * mean;
    const float rstd = rsqrtf(var + 1e-5f);
    float4 wv4 = ((const float4*)w)[tid];
    float4 bv4 = ((const float4*)b)[tid];
    uint2 o;
    o.x = (uint_t)f2bfu((xv.x - mean) * rstd * wv4.x + bv4.x)
        | ((uint_t)f2bfu((xv.y - mean) * rstd * wv4.y + bv4.y) << 16);
    o.y = (uint_t)f2bfu((xv.z - mean) * rstd * wv4.z + bv4.z)
        | ((uint_t)f2bfu((xv.w - mean) * rstd * wv4.w + bv4.w) << 16);
    ((uint2*)(out + (size_t)row * C_))[tid] = o;
}

// =====================================================================
// gate[m,h] = sigmoid(dot(xx[m,:], w_g[h,:])), xx computed inline
// =====================================================================
__global__ __launch_bounds__(256) void gate_kernel(const ushort_t* __restrict__ h,
                                                   const float* __restrict__ wg,
                                                   float* __restrict__ gate) {
    __shared__ float xr[C_];
    const int row = blockIdx.x;
    const int tid = threadIdx.x;
    const int t = row & (T_ - 1);
    uint2 cu = *(const uint2*)(h + (size_t)row * C_ + tid * 4);
    uint2 pu = make_uint2(0u, 0u);
    if (t > 0) pu = *(const uint2*)(h + (size_t)(row - 1) * C_ + tid * 4);
    xr[tid * 4 + 0] = bfu2f((ushort_t)(pu.x & 0xffffu)) - bfu2f((ushort_t)(cu.x & 0xffffu));
    xr[tid * 4 + 1] = bfu2f((ushort_t)(pu.x >> 16))     - bfu2f((ushort_t)(cu.x >> 16));
    xr[tid * 4 + 2] = bfu2f((ushort_t)(pu.y & 0xffffu)) - bfu2f((ushort_t)(cu.y & 0xffffu));
    xr[tid * 4 + 3] = bfu2f((ushort_t)(pu.y >> 16))     - bfu2f((ushort_t)(cu.y >> 16));
    __syncthreads();
    const int wv = tid >> 6, ln = tid & 63;
#pragma unroll
    for (int hh = 0; hh < 4; ++hh) {
        const int h_ = wv * 4 + hh;
        const float* wrow = wg + (size_t)h_ * C_;
        float acc = 0.f;
#pragma unroll
        for (int i = 0; i < 16; ++i) { int c = i * 64 + ln; acc += xr[c] * wrow[c]; }
#pragma unroll
        for (int off = 32; off; off >>= 1) acc += __shfl_down(acc, off);
        if (ln == 0) gate[(size_t)row * H_ + h_] = 1.f / (1.f + __expf(-acc));
    }
}

// =====================================================================
// wkv fwd+bwd scan (decay 0.5), restructured: parallel LDS staging of the
// v window, 4 independent in-LDS scans (fwd/bwd x two 64-t halves), then
// fully parallel vectorized combine. Edge clamping of the 32-row warmup
// window reproduces the original warmup semantics exactly (replicated
// edge rows keep the carry fixed at v[0] / v[T-1]).
// Block = 256 threads, LDS = 48 + 16 + 16 = 80 KB -> 2 blocks/CU.
// =====================================================================
__global__ __launch_bounds__(256) void wkv_combine_kernel(const float* __restrict__ v,
                                                          const ushort_t* __restrict__ r,
                                                          const float* __restrict__ gate,
                                                          ushort_t* __restrict__ xc) {
    __shared__ float    vbuf[192 * 64];   // 48 KB, row i = t0-32+i (clamped)
    __shared__ ushort_t fb[128 * 64];     // 16 KB, fwd (bf16)
    __shared__ ushort_t bb[128 * 64];     // 16 KB, bwd (bf16)
    const int blk = blockIdx.x;           // b*256 + h*16 + chunk
    const int chunk = blk & 15;
    const int bh = blk >> 4;
    const int h = bh & 15;
    const int b = bh >> 4;
    const int t0 = chunk * 128;
    const int tid = threadIdx.x;

    // ---- phase 1: stage v[t0-32 .. t0+160) (clamped) into LDS ----
    {
        const float* vb = v + ((size_t)b * T_) * C_ + h * 64;
#pragma unroll
        for (int j = 0; j < 12; ++j) {
            int idx = j * 256 + tid;      // 0..3071
            int row = idx >> 4, q = idx & 15;
            int t = t0 - 32 + row;
            t = t < 0 ? 0 : (t > T_ - 1 ? T_ - 1 : t);
            float4 val = *(const float4*)(vb + (size_t)t * C_ + q * 4);
            *(float4*)(vbuf + row * 64 + q * 4) = val;
        }
    }
    __syncthreads();

    // ---- phase 2: 4 independent scans over LDS ----
    const int wv = tid >> 6, n = tid & 63;
    const int half = wv & 1;              // which 64-t half of the chunk
    if (wv < 2) {
        // forward: outputs t-t0 in [64*half, 64*half+64)
        const int s = 64 * half;          // start row (t = t0-32+s)
        float carry = vbuf[s * 64 + n];
#pragma unroll
        for (int i = 1; i < 32; ++i)
            carry = 0.5f * (carry + vbuf[(s + i) * 64 + n]);
#pragma unroll 8
        for (int i = 32; i <= 95; ++i) {
            carry = 0.5f * (carry + vbuf[(s + i) * 64 + n]);
            int trel = s + i - 32;
            fb[trel * 64 + n] = f2bfu(carry);
        }
    } else {
        // backward: outputs t-t0 in [64*half, 64*half+64)
        const int e = 64 * half + 127;    // start row (t = t0+64*half+95)
        float carry = vbuf[e * 64 + n];
#pragma unroll
        for (int i = 1; i < 32; ++i)
            carry = 0.5f * (carry + vbuf[(e - i) * 64 + n]);
#pragma unroll 8
        for (int i = 32; i <= 95; ++i) {
            carry = 0.5f * (carry + vbuf[(e - i) * 64 + n]);
            int trel = e - i - 32;
            bb[trel * 64 + n] = f2bfu(carry);
        }
    }
    __syncthreads();

    // ---- phase 3: combine xc = r * (g*fwd + (1-g)*bwd), vectorized x2 ----
    const size_t rowbase = ((size_t)b * T_ + t0) * C_ + h * 64;
    const size_t gbase = ((size_t)b * T_ + t0) * H_ + h;
#pragma unroll
    for (int i = 0; i < 16; ++i) {
        int idx = i * 512 + tid * 2;      // 0..8190, even
        int trow = idx >> 6, nn = idx & 63;
        uint_t fu = *(const uint_t*)(fb + idx);
        uint_t bu = *(const uint_t*)(bb + idx);
        uint_t ru = *(const uint_t*)(r + rowbase + (size_t)trow * C_ + nn);
        float g = gate[gbase + (size_t)trow * H_];
        float f0 = bfu2f((ushort_t)(fu & 0xffffu)), f1 = bfu2f((ushort_t)(fu >> 16));
        float b0 = bfu2f((ushort_t)(bu & 0xffffu)), b1 = bfu2f((ushort_t)(bu >> 16));
        float r0 = bfu2f((ushort_t)(ru & 0xffffu)), r1 = bfu2f((ushort_t)(ru >> 16));
        float o0 = r0 * (g * f0 + (1.f - g) * b0);
        float o1 = r1 * (g * f1 + (1.f - g) * b1);
        *(uint_t*)(xc + rowbase + (size_t)trow * C_ + nn) =
            (uint_t)f2bfu(o0) | ((uint_t)f2bfu(o1) << 16);
    }
}

// =====================================================================
// 256x256 pipelined bf16 GEMM. C[M,N] = A[M,K] * B[N,K]^T.
// 8 waves (2m x 4n), BK=64, 128KiB LDS dbuf, per wave 128x64 = acc[8][4].
// Register-fragment pipeline: every MFMA's ds_reads issue >=1 phase before
// use -> compiler emits counted lgkmcnt -> LDS latency hides under MFMA.
// One s_barrier per phase (4/tile). Counted vmcnt(4)/vmcnt(2), never 0.
// LDS swizzle: byte ^= (row&7)<<4 on reads; linear LDS dest + inverse-
// swizzled per-lane GLOBAL source for global_load_lds.
// SHIFT: A row m reads row m-1 (t==0 rows -> zero page).
// EPI: 0 bf16; 1 f32; 2 f32 extra+acc; 3 relu^2 bf16
// =====================================================================
#define BAR() do { asm volatile("" ::: "memory"); \
                   __builtin_amdgcn_s_barrier(); \
                   asm volatile("" ::: "memory"); } while (0)
#define SETP(x) __builtin_amdgcn_s_setprio(x)
#define SCHEDB() __builtin_amdgcn_sched_barrier(0)
#define VMCNT(n) asm volatile("s_waitcnt vmcnt(" #n ")" ::: "memory")

template <int EPI, bool SHIFT>
__global__ __launch_bounds__(512, 2) void gemm256(const ushort_t* __restrict__ A,
                                                  const ushort_t* __restrict__ Bm,
                                                  const float* __restrict__ extra,
                                                  float* __restrict__ outF,
                                                  ushort_t* __restrict__ outB,
                                                  const ushort_t* __restrict__ zpage,
                                                  int N, int K) {
    __shared__ ushort_t As[2][256 * 64];   // 64 KB
    __shared__ ushort_t Bs[2][256 * 64];   // 64 KB
    const int NT = K >> 6;                 // K-tiles (even >=2 for all shapes here)
    const int tid = threadIdx.x;
    const int lane = tid & 63, wv = tid >> 6;
    const int wm = wv >> 2, wn = wv & 3;   // 2 x 4 wave grid
    const size_t m0 = (size_t)(blockIdx.x & 63) * 256;   // Mtiles = 64 always
    const size_t n0 = (size_t)(blockIdx.x >> 6) * 256;

    // ---- staging: per-lane pre-swizzled global sources ----
    const int l8 = lane >> 3;
    const int swcol = ((lane & 7) ^ l8) * 8;   // elements
    const ushort_t* pA[2][2];
    const ushort_t* pB[2][2];
#pragma unroll
    for (int hf = 0; hf < 2; ++hf)
#pragma unroll
        for (int i8 = 0; i8 < 2; ++i8) {
            const size_t tr = (size_t)(hf * 128 + wv * 16 + i8 * 8 + l8);
            const size_t mrow = m0 + tr, nrow = n0 + tr;
            if (SHIFT)
                pA[hf][i8] = ((mrow & (size_t)(T_ - 1)) == 0)
                                 ? (zpage + swcol)
                                 : (A + (mrow - 1) * (size_t)K + swcol);
            else
                pA[hf][i8] = A + mrow * (size_t)K + swcol;
            pB[hf][i8] = Bm + nrow * (size_t)K + swcol;
        }

    // ---- swizzled fragment-read offsets ----
    const int rl = lane & 15;
    const int swz = (lane & 7) << 4;           // (row&7)<<4
    const int cq = (lane >> 4) << 4;           // (lane>>4)*16 bytes
    const int offk0 = cq ^ swz;                // kk=0
    const int offk1 = (64 | cq) ^ swz;         // kk=1 (+32 elements)
    const int aRow = (wm * 128 + rl) * 128;    // byte offset of frag row
    const int bRow = (wn * 64 + rl) * 128;

    bf16x8 a[8], b0[4], b1[4];
    f32x4 acc[8][4];
#pragma unroll
    for (int i = 0; i < 8; ++i)
#pragma unroll
        for (int j = 0; j < 4; ++j) acc[i][j] = (f32x4){0.f, 0.f, 0.f, 0.f};

#define STAGE_A(BUF, HF, KOF) do { \
    gl_lds16(pA[HF][0] + (KOF), &As[BUF][((HF) * 128 + wv * 16 + 0) * 64]); \
    gl_lds16(pA[HF][1] + (KOF), &As[BUF][((HF) * 128 + wv * 16 + 8) * 64]); } while (0)
#define STAGE_B(BUF, HF, KOF) do { \
    gl_lds16(pB[HF][0] + (KOF), &Bs[BUF][((HF) * 128 + wv * 16 + 0) * 64]); \
    gl_lds16(pB[HF][1] + (KOF), &Bs[BUF][((HF) * 128 + wv * 16 + 8) * 64]); } while (0)
#define LOAD_A(ARR, BUF, QM) do { \
    const char* _ab = (const char*)As[BUF] + aRow + (QM) * 64 * 128; \
    _Pragma("unroll") \
    for (int mi = 0; mi < 4; ++mi) { \
        ARR[mi * 2 + 0] = *(const bf16x8*)(_ab + mi * 16 * 128 + offk0); \
        ARR[mi * 2 + 1] = *(const bf16x8*)(_ab + mi * 16 * 128 + offk1); } } while (0)
#define LOAD_B(ARR, BUF, QN) do { \
    const char* _bb = (const char*)Bs[BUF] + bRow + (QN) * 32 * 128; \
    _Pragma("unroll") \
    for (int ni = 0; ni < 2; ++ni) { \
        ARR[ni * 2 + 0] = *(const bf16x8*)(_bb + ni * 16 * 128 + offk0); \
        ARR[ni * 2 + 1] = *(const bf16x8*)(_bb + ni * 16 * 128 + offk1); } } while (0)
#define MFMA_Q(AARR, BARR, QM, QN) do { \
    _Pragma("unroll") \
    for (int mi = 0; mi < 4; ++mi) \
    _Pragma("unroll") \
    for (int ni = 0; ni < 2; ++ni) { \
        acc[(QM)*4+mi][(QN)*2+ni] = __builtin_amdgcn_mfma_f32_16x16x32_bf16( \
            AARR[mi*2+0], BARR[ni*2+0], acc[(QM)*4+mi][(QN)*2+ni], 0, 0, 0); \
        acc[(QM)*4+mi][(QN)*2+ni] = __builtin_amdgcn_mfma_f32_16x16x32_bf16( \
            AARR[mi*2+1], BARR[ni*2+1], acc[(QM)*4+mi][(QN)*2+ni], 0, 0, 0); } } while (0)

#define KTILE(CB, OB, KT) do { \
    const int _kA = ((KT) + 1 < NT) ? ((KT) + 1) * 64 : 0; \
    const int _kB = ((KT) + 2 < NT) ? ((KT) + 2) * 64 : 0; \
    BAR(); \
    LOAD_B(b1, CB, 1); \
    STAGE_A(OB, 0, _kA); \
    SETP(1); MFMA_Q(a, b0, 0, 0); SETP(0); \
    BAR(); \
    STAGE_A(OB, 1, _kA); \
    SETP(1); MFMA_Q(a, b1, 0, 1); SETP(0); \
    SCHEDB(); \
    LOAD_A(a, CB, 1); \
    VMCNT(4); \
    BAR(); \
    STAGE_B(CB, 0, _kB); \
    SETP(1); MFMA_Q(a, b0, 1, 0); SETP(0); \
    VMCNT(2); \
    BAR(); \
    LOAD_B(b0, OB, 0); \
    STAGE_B(CB, 1, _kB); \
    SETP(1); MFMA_Q(a, b1, 1, 1); SETP(0); \
    SCHEDB(); \
    LOAD_A(a, OB, 0); \
  } while (0)

    // prologue
    STAGE_A(0, 0, 0); STAGE_A(0, 1, 0);
    STAGE_B(0, 0, 0); STAGE_B(0, 1, 0);
    const int _k1 = (NT > 1) ? 64 : 0;
    STAGE_B(1, 0, _k1); STAGE_B(1, 1, _k1);
    VMCNT(4);
    BAR();
    LOAD_A(a, 0, 0);
    LOAD_B(b0, 0, 0);

    for (int kt = 0; kt < NT; kt += 2) {
        KTILE(0, 1, kt);
        KTILE(1, 0, kt + 1);
    }

#undef KTILE
#undef MFMA_Q
#undef LOAD_B
#undef LOAD_A
#undef STAGE_B
#undef STAGE_A

    // epilogue: C/D layout col=lane&15, row=(lane>>4)*4+reg
    const int crow = (lane >> 4) * 4;
    const int ccol = lane & 15;
#pragma unroll
    for (int mi = 0; mi < 8; ++mi) {
#pragma unroll
        for (int ni = 0; ni < 4; ++ni) {
#pragma unroll
            for (int rr = 0; rr < 4; ++rr) {
                size_t row = m0 + wm * 128 + mi * 16 + crow + rr;
                size_t col = n0 + wn * 64 + ni * 16 + ccol;
                size_t oix = row * (size_t)N + col;
                float v = acc[mi][ni][rr];
                if (EPI == 0)      outB[oix] = f2bfu(v);
                else if (EPI == 1) outF[oix] = v;
                else if (EPI == 2) outF[oix] = extra[oix] + v;
                else { float t = v > 0.f ? v : 0.f; outB[oix] = f2bfu(t * t); }
            }
        }
    }
}

// =====================================================================
// launcher
// =====================================================================
extern "C" void kernel_launch(void* const* d_in, const int* in_sizes, int n_in,
                              void* d_out, int out_size, void* d_ws, size_t ws_size,
                              hipStream_t stream) {
    const float* x    = (const float*)d_in[0];
    const float* ln1w = (const float*)d_in[2];
    const float* ln1b = (const float*)d_in[3];
    const float* ln2w = (const float*)d_in[4];
    const float* ln2b = (const float*)d_in[5];
    const float* w_r  = (const float*)d_in[6];
    // d_in[7] = w_k: unused by the reference's _wkv — skipped.
    const float* w_v  = (const float*)d_in[8];
    const float* w_o  = (const float*)d_in[9];
    const float* w_g  = (const float*)d_in[10];
    const float* ck_w = (const float*)d_in[11];
    const float* cv_w = (const float*)d_in[12];

    float* out0 = (float*)d_out;                       // x1 + ffn_out  [M,C]
    float* vout = out0 + (size_t)M_ * C_;              // v_first_out   [M,C] fp32

    char* ws = (char*)d_ws;
    const size_t MB = 1024ull * 1024ull;
    ushort_t* wr_bf = (ushort_t*)(ws + 0 * MB);        // 2MB
    ushort_t* wv_bf = (ushort_t*)(ws + 2 * MB);        // 2MB
    ushort_t* wo_bf = (ushort_t*)(ws + 4 * MB);        // 2MB
    ushort_t* ck_bf = (ushort_t*)(ws + 6 * MB);        // 8MB
    ushort_t* cv_bf = (ushort_t*)(ws + 14 * MB);       // 8MB
    float*    gate  = (float*)(ws + 22 * MB);          // 1MB
    ushort_t* zpage = (ushort_t*)(ws + 23 * MB);       // 16KB (1MB slot)
    ushort_t* bufA  = (ushort_t*)(ws + 24 * MB);       // 32MB  h1, later h2
    ushort_t* bufC  = (ushort_t*)(ws + 56 * MB);       // 32MB  x_comb
    ushort_t* r_bf  = (ushort_t*)(ws + 88 * MB);       // 32MB
    float*    x1    = (float*)(ws + 120 * MB);         // 64MB
    ushort_t* k2p   = (ushort_t*)(ws + 184 * MB);      // 128MB; total 312MB

    // weights fp32 -> bf16; zero page for shifted GEMM rows
    f2bf3_kernel<<<dim3(C_ * C_ / 1024, 3), 256, 0, stream>>>(w_r, w_v, w_o, wr_bf, wv_bf, wo_bf);
    f2bf2_kernel<<<dim3(FC_ * C_ / 1024, 2), 256, 0, stream>>>(ck_w, cv_w, ck_bf, cv_bf);
    hipMemsetAsync(zpage, 0, 16384, stream);

    // h = LN1(x)
    ln_kernel<<<M_, 256, 0, stream>>>(x, ln1w, ln1b, bufA);

    // gate = sigmoid((shift(h)-h) @ w_g^T)
    gate_kernel<<<M_, 256, 0, stream>>>(bufA, w_g, gate);

    // r = shift(h) @ w_r^T (bf16); v = shift(h) @ w_v^T (fp32, = output 1)
    gemm256<0, true><<<(M_ / 256) * (C_ / 256), 512, 0, stream>>>(bufA, wr_bf, nullptr, nullptr, r_bf, zpage, C_, C_);
    gemm256<1, true><<<(M_ / 256) * (C_ / 256), 512, 0, stream>>>(bufA, wv_bf, nullptr, vout, nullptr, zpage, C_, C_);

    // wkv fwd+bwd + combine -> x_comb
    wkv_combine_kernel<<<B_ * H_ * (T_ / 128), 256, 0, stream>>>(vout, r_bf, gate, bufC);

    // x1 = x + x_comb @ w_o^T
    gemm256<2, false><<<(M_ / 256) * (C_ / 256), 512, 0, stream>>>(bufC, wo_bf, x, x1, nullptr, zpage, C_, C_);

    // h2 = LN2(x1)
    ln_kernel<<<M_, 256, 0, stream>>>(x1, ln2w, ln2b, bufA);

    // k2p = relu(shift(h2) @ ck_w^T)^2; out0 = x1 + k2p @ cv_w^T
    gemm256<3, true><<<(M_ / 256) * (FC_ / 256), 512, 0, stream>>>(bufA, ck_bf, nullptr, nullptr, k2p, zpage, FC_, C_);
    gemm256<2, false><<<(M_ / 256) * (C_ / 256), 512, 0, stream>>>(k2p, cv_bf, x1, out0, nullptr, zpage, C_, FC_);
}

// Round 4
// 730.164 us; speedup vs baseline: 1.2381x; 1.0146x over previous
//
#include <hip/hip_runtime.h>

// ---- problem constants ----
constexpr int B_ = 8, T_ = 2048, C_ = 1024, H_ = 16, N_ = 64;
constexpr int M_ = B_ * T_;              // 16384 rows
constexpr int FC_ = 4 * C_;              // 4096

typedef __attribute__((ext_vector_type(8))) short bf16x8;
typedef __attribute__((ext_vector_type(4))) float f32x4;
typedef unsigned short ushort_t;
typedef unsigned int uint_t;

__device__ __forceinline__ float bfu2f(ushort_t u) {
    union { uint_t i; float f; } c; c.i = ((uint_t)u) << 16; return c.f;
}
__device__ __forceinline__ ushort_t f2bfu(float f) {
    union { float f; uint_t i; } c; c.f = f;
    uint_t i = c.i;
    uint_t r = i + 0x7FFFu + ((i >> 16) & 1u);   // round-to-nearest-even
    return (ushort_t)(r >> 16);
}

__device__ __forceinline__ void gl_lds16(const void* g, void* l) {
    __builtin_amdgcn_global_load_lds(
        (const __attribute__((address_space(1))) void*)g,
        (__attribute__((address_space(3))) void*)l, 16, 0, 0);
}

// =====================================================================
// fp32 -> bf16 weight converts, folded into 2 launches
// =====================================================================
__global__ __launch_bounds__(256) void f2bf3_kernel(const float* __restrict__ a,
                                                    const float* __restrict__ b,
                                                    const float* __restrict__ c,
                                                    ushort_t* __restrict__ oa,
                                                    ushort_t* __restrict__ ob,
                                                    ushort_t* __restrict__ oc) {
    const float* in = (blockIdx.y == 0) ? a : (blockIdx.y == 1) ? b : c;
    ushort_t* out   = (blockIdx.y == 0) ? oa : (blockIdx.y == 1) ? ob : oc;
    size_t i = ((size_t)blockIdx.x * 256 + threadIdx.x) * 4;
    float4 v = *(const float4*)(in + i);
    uint2 o;
    o.x = (uint_t)f2bfu(v.x) | ((uint_t)f2bfu(v.y) << 16);
    o.y = (uint_t)f2bfu(v.z) | ((uint_t)f2bfu(v.w) << 16);
    *(uint2*)(out + i) = o;
}

__global__ __launch_bounds__(256) void f2bf2_kernel(const float* __restrict__ a,
                                                    const float* __restrict__ b,
                                                    ushort_t* __restrict__ oa,
                                                    ushort_t* __restrict__ ob) {
    const float* in = (blockIdx.y == 0) ? a : b;
    ushort_t* out   = (blockIdx.y == 0) ? oa : ob;
    size_t i = ((size_t)blockIdx.x * 256 + threadIdx.x) * 4;
    float4 v = *(const float4*)(in + i);
    uint2 o;
    o.x = (uint_t)f2bfu(v.x) | ((uint_t)f2bfu(v.y) << 16);
    o.y = (uint_t)f2bfu(v.z) | ((uint_t)f2bfu(v.w) << 16);
    *(uint2*)(out + i) = o;
}

// =====================================================================
// LayerNorm over C=1024, one block per row, output bf16
// =====================================================================
__global__ __launch_bounds__(256) void ln_kernel(const float* __restrict__ x,
                                                 const float* __restrict__ w,
                                                 const float* __restrict__ b,
                                                 ushort_t* __restrict__ out) {
    const int row = blockIdx.x;
    const int tid = threadIdx.x;
    const float* xr = x + (size_t)row * C_;
    float4 xv = ((const float4*)xr)[tid];
    float s  = xv.x + xv.y + xv.z + xv.w;
    float ss = xv.x*xv.x + xv.y*xv.y + xv.z*xv.z + xv.w*xv.w;
#pragma unroll
    for (int off = 32; off; off >>= 1) { s += __shfl_down(s, off); ss += __shfl_down(ss, off); }
    __shared__ float sb[8];
    const int wv = tid >> 6, ln = tid & 63;
    if (ln == 0) { sb[wv] = s; sb[4 + wv] = ss; }
    __syncthreads();
    s  = sb[0] + sb[1] + sb[2] + sb[3];
    ss = sb[4] + sb[5] + sb[6] + sb[7];
    const float mean = s * (1.f / C_);
    const float var  = ss * (1.f / C_) - mean * mean;
    const float rstd = rsqrtf(var + 1e-5f);
    float4 wv4 = ((const float4*)w)[tid];
    float4 bv4 = ((const float4*)b)[tid];
    uint2 o;
    o.x = (uint_t)f2bfu((xv.x - mean) * rstd * wv4.x + bv4.x)
        | ((uint_t)f2bfu((xv.y - mean) * rstd * wv4.y + bv4.y) << 16);
    o.y = (uint_t)f2bfu((xv.z - mean) * rstd * wv4.z + bv4.z)
        | ((uint_t)f2bfu((xv.w - mean) * rstd * wv4.w + bv4.w) << 16);
    ((uint2*)(out + (size_t)row * C_))[tid] = o;
}

// =====================================================================
// gate[m,h] = sigmoid(dot(xx[m,:], w_g[h,:])), xx computed inline
// =====================================================================
__global__ __launch_bounds__(256) void gate_kernel(const ushort_t* __restrict__ h,
                                                   const float* __restrict__ wg,
                                                   float* __restrict__ gate) {
    __shared__ float xr[C_];
    const int row = blockIdx.x;
    const int tid = threadIdx.x;
    const int t = row & (T_ - 1);
    uint2 cu = *(const uint2*)(h + (size_t)row * C_ + tid * 4);
    uint2 pu = make_uint2(0u, 0u);
    if (t > 0) pu = *(const uint2*)(h + (size_t)(row - 1) * C_ + tid * 4);
    xr[tid * 4 + 0] = bfu2f((ushort_t)(pu.x & 0xffffu)) - bfu2f((ushort_t)(cu.x & 0xffffu));
    xr[tid * 4 + 1] = bfu2f((ushort_t)(pu.x >> 16))     - bfu2f((ushort_t)(cu.x >> 16));
    xr[tid * 4 + 2] = bfu2f((ushort_t)(pu.y & 0xffffu)) - bfu2f((ushort_t)(cu.y & 0xffffu));
    xr[tid * 4 + 3] = bfu2f((ushort_t)(pu.y >> 16))     - bfu2f((ushort_t)(cu.y >> 16));
    __syncthreads();
    const int wv = tid >> 6, ln = tid & 63;
#pragma unroll
    for (int hh = 0; hh < 4; ++hh) {
        const int h_ = wv * 4 + hh;
        const float* wrow = wg + (size_t)h_ * C_;
        float acc = 0.f;
#pragma unroll
        for (int i = 0; i < 16; ++i) { int c = i * 64 + ln; acc += xr[c] * wrow[c]; }
#pragma unroll
        for (int off = 32; off; off >>= 1) acc += __shfl_down(acc, off);
        if (ln == 0) gate[(size_t)row * H_ + h_] = 1.f / (1.f + __expf(-acc));
    }
}

// =====================================================================
// wkv fwd+bwd scan (decay 0.5), parallel LDS staging + 4 independent
// in-LDS scans + vectorized combine. Edge clamping reproduces warmup.
// =====================================================================
__global__ __launch_bounds__(256) void wkv_combine_kernel(const float* __restrict__ v,
                                                          const ushort_t* __restrict__ r,
                                                          const float* __restrict__ gate,
                                                          ushort_t* __restrict__ xc) {
    __shared__ float    vbuf[192 * 64];   // 48 KB, row i = t0-32+i (clamped)
    __shared__ ushort_t fb[128 * 64];     // 16 KB, fwd (bf16)
    __shared__ ushort_t bb[128 * 64];     // 16 KB, bwd (bf16)
    const int blk = blockIdx.x;           // b*256 + h*16 + chunk
    const int chunk = blk & 15;
    const int bh = blk >> 4;
    const int h = bh & 15;
    const int b = bh >> 4;
    const int t0 = chunk * 128;
    const int tid = threadIdx.x;

    // ---- phase 1: stage v[t0-32 .. t0+160) (clamped) into LDS ----
    {
        const float* vb = v + ((size_t)b * T_) * C_ + h * 64;
#pragma unroll
        for (int j = 0; j < 12; ++j) {
            int idx = j * 256 + tid;      // 0..3071
            int row = idx >> 4, q = idx & 15;
            int t = t0 - 32 + row;
            t = t < 0 ? 0 : (t > T_ - 1 ? T_ - 1 : t);
            float4 val = *(const float4*)(vb + (size_t)t * C_ + q * 4);
            *(float4*)(vbuf + row * 64 + q * 4) = val;
        }
    }
    __syncthreads();

    // ---- phase 2: 4 independent scans over LDS ----
    const int wv = tid >> 6, n = tid & 63;
    const int half = wv & 1;              // which 64-t half of the chunk
    if (wv < 2) {
        const int s = 64 * half;          // start row (t = t0-32+s)
        float carry = vbuf[s * 64 + n];
#pragma unroll
        for (int i = 1; i < 32; ++i)
            carry = 0.5f * (carry + vbuf[(s + i) * 64 + n]);
#pragma unroll 8
        for (int i = 32; i <= 95; ++i) {
            carry = 0.5f * (carry + vbuf[(s + i) * 64 + n]);
            int trel = s + i - 32;
            fb[trel * 64 + n] = f2bfu(carry);
        }
    } else {
        const int e = 64 * half + 127;    // start row (t = t0+64*half+95)
        float carry = vbuf[e * 64 + n];
#pragma unroll
        for (int i = 1; i < 32; ++i)
            carry = 0.5f * (carry + vbuf[(e - i) * 64 + n]);
#pragma unroll 8
        for (int i = 32; i <= 95; ++i) {
            carry = 0.5f * (carry + vbuf[(e - i) * 64 + n]);
            int trel = e - i - 32;
            bb[trel * 64 + n] = f2bfu(carry);
        }
    }
    __syncthreads();

    // ---- phase 3: combine xc = r * (g*fwd + (1-g)*bwd), vectorized x2 ----
    const size_t rowbase = ((size_t)b * T_ + t0) * C_ + h * 64;
    const size_t gbase = ((size_t)b * T_ + t0) * H_ + h;
#pragma unroll
    for (int i = 0; i < 16; ++i) {
        int idx = i * 512 + tid * 2;      // 0..8190, even
        int trow = idx >> 6, nn = idx & 63;
        uint_t fu = *(const uint_t*)(fb + idx);
        uint_t bu = *(const uint_t*)(bb + idx);
        uint_t ru = *(const uint_t*)(r + rowbase + (size_t)trow * C_ + nn);
        float g = gate[gbase + (size_t)trow * H_];
        float f0 = bfu2f((ushort_t)(fu & 0xffffu)), f1 = bfu2f((ushort_t)(fu >> 16));
        float b0 = bfu2f((ushort_t)(bu & 0xffffu)), b1 = bfu2f((ushort_t)(bu >> 16));
        float r0 = bfu2f((ushort_t)(ru & 0xffffu)), r1 = bfu2f((ushort_t)(ru >> 16));
        float o0 = r0 * (g * f0 + (1.f - g) * b0);
        float o1 = r1 * (g * f1 + (1.f - g) * b1);
        *(uint_t*)(xc + rowbase + (size_t)trow * C_ + nn) =
            (uint_t)f2bfu(o0) | ((uint_t)f2bfu(o1) << 16);
    }
}

// =====================================================================
// 256x256 pipelined bf16 GEMM. C[M,N] = A[M,K] * B[N,K]^T.
// 8 waves (2m x 4n), BK=64, 128KiB LDS dbuf, per wave 128x64 = acc[8][4].
// Register-fragment pipeline (reads >=1 phase before use) PLUS deep
// staging: both operands staged TWO K-tiles ahead into the current tile's
// buffers right after their last read; single vmcnt(6)/tile (issue->drain
// distance >=3 phases ~ 2000 cyc >> 900-cyc HBM latency).
// LDS swizzle byte^=(row&7)<<4 on reads; linear LDS dest + inverse-
// swizzled per-lane GLOBAL source for global_load_lds.
// SHIFT: A row m reads row m-1 (t==0 rows -> zero page).
// EPI: 0 bf16; 1 f32; 2 f32 extra+acc; 3 relu^2 bf16
// =====================================================================
#define BAR() do { asm volatile("" ::: "memory"); \
                   __builtin_amdgcn_s_barrier(); \
                   asm volatile("" ::: "memory"); } while (0)
#define SETP(x) __builtin_amdgcn_s_setprio(x)
#define SCHEDB() __builtin_amdgcn_sched_barrier(0)
#define VMCNT(n) asm volatile("s_waitcnt vmcnt(" #n ")" ::: "memory")

template <int EPI, bool SHIFT>
__global__ __launch_bounds__(512, 2) void gemm256(const ushort_t* __restrict__ A,
                                                  const ushort_t* __restrict__ Bm,
                                                  const float* __restrict__ extra,
                                                  float* __restrict__ outF,
                                                  ushort_t* __restrict__ outB,
                                                  const ushort_t* __restrict__ zpage,
                                                  int N, int K) {
    __shared__ ushort_t As[2][256 * 64];   // 64 KB
    __shared__ ushort_t Bs[2][256 * 64];   // 64 KB
    const int NT = K >> 6;                 // K-tiles (even >=2 for all shapes here)
    const int tid = threadIdx.x;
    const int lane = tid & 63, wv = tid >> 6;
    const int wm = wv >> 2, wn = wv & 3;   // 2 x 4 wave grid
    const size_t m0 = (size_t)(blockIdx.x & 63) * 256;   // Mtiles = 64 always
    const size_t n0 = (size_t)(blockIdx.x >> 6) * 256;

    // ---- staging: per-lane pre-swizzled global sources ----
    const int l8 = lane >> 3;
    const int swcol = ((lane & 7) ^ l8) * 8;   // elements
    const ushort_t* pA[2][2];
    const ushort_t* pB[2][2];
#pragma unroll
    for (int hf = 0; hf < 2; ++hf)
#pragma unroll
        for (int i8 = 0; i8 < 2; ++i8) {
            const size_t tr = (size_t)(hf * 128 + wv * 16 + i8 * 8 + l8);
            const size_t mrow = m0 + tr, nrow = n0 + tr;
            if (SHIFT)
                pA[hf][i8] = ((mrow & (size_t)(T_ - 1)) == 0)
                                 ? (zpage + swcol)
                                 : (A + (mrow - 1) * (size_t)K + swcol);
            else
                pA[hf][i8] = A + mrow * (size_t)K + swcol;
            pB[hf][i8] = Bm + nrow * (size_t)K + swcol;
        }

    // ---- swizzled fragment-read offsets ----
    const int rl = lane & 15;
    const int swz = (lane & 7) << 4;           // (row&7)<<4
    const int cq = (lane >> 4) << 4;           // (lane>>4)*16 bytes
    const int offk0 = cq ^ swz;                // kk=0
    const int offk1 = (64 | cq) ^ swz;         // kk=1 (+32 elements)
    const int aRow = (wm * 128 + rl) * 128;    // byte offset of frag row
    const int bRow = (wn * 64 + rl) * 128;

    bf16x8 a[8], b0[4], b1[4];
    f32x4 acc[8][4];
#pragma unroll
    for (int i = 0; i < 8; ++i)
#pragma unroll
        for (int j = 0; j < 4; ++j) acc[i][j] = (f32x4){0.f, 0.f, 0.f, 0.f};

#define STAGE_A(BUF, HF, KOF) do { \
    gl_lds16(pA[HF][0] + (KOF), &As[BUF][((HF) * 128 + wv * 16 + 0) * 64]); \
    gl_lds16(pA[HF][1] + (KOF), &As[BUF][((HF) * 128 + wv * 16 + 8) * 64]); } while (0)
#define STAGE_B(BUF, HF, KOF) do { \
    gl_lds16(pB[HF][0] + (KOF), &Bs[BUF][((HF) * 128 + wv * 16 + 0) * 64]); \
    gl_lds16(pB[HF][1] + (KOF), &Bs[BUF][((HF) * 128 + wv * 16 + 8) * 64]); } while (0)
#define LOAD_A(ARR, BUF, QM) do { \
    const char* _ab = (const char*)As[BUF] + aRow + (QM) * 64 * 128; \
    _Pragma("unroll") \
    for (int mi = 0; mi < 4; ++mi) { \
        ARR[mi * 2 + 0] = *(const bf16x8*)(_ab + mi * 16 * 128 + offk0); \
        ARR[mi * 2 + 1] = *(const bf16x8*)(_ab + mi * 16 * 128 + offk1); } } while (0)
#define LOAD_B(ARR, BUF, QN) do { \
    const char* _bb = (const char*)Bs[BUF] + bRow + (QN) * 32 * 128; \
    _Pragma("unroll") \
    for (int ni = 0; ni < 2; ++ni) { \
        ARR[ni * 2 + 0] = *(const bf16x8*)(_bb + ni * 16 * 128 + offk0); \
        ARR[ni * 2 + 1] = *(const bf16x8*)(_bb + ni * 16 * 128 + offk1); } } while (0)
#define MFMA_Q(AARR, BARR, QM, QN) do { \
    _Pragma("unroll") \
    for (int mi = 0; mi < 4; ++mi) \
    _Pragma("unroll") \
    for (int ni = 0; ni < 2; ++ni) { \
        acc[(QM)*4+mi][(QN)*2+ni] = __builtin_amdgcn_mfma_f32_16x16x32_bf16( \
            AARR[mi*2+0], BARR[ni*2+0], acc[(QM)*4+mi][(QN)*2+ni], 0, 0, 0); \
        acc[(QM)*4+mi][(QN)*2+ni] = __builtin_amdgcn_mfma_f32_16x16x32_bf16( \
            AARR[mi*2+1], BARR[ni*2+1], acc[(QM)*4+mi][(QN)*2+ni], 0, 0, 0); } } while (0)

// Tile t (CB=t&1, OB=CB^1). Entering: a=a0(t), b0=b0(t) (read at t-1.P3).
// P0: rd b1(t)<-B[CB];                           MFMA Q00(a0,b0)
// P1: st B(t+2)h0->B[CB];                        MFMA Q01(a0,b1); rd a1(t)<-A[CB]
// P2: st B(t+2)h1->B[CB]; st A(t+2)h0->A[CB];    MFMA Q10(a1,b0); vmcnt(6)
// P3: st A(t+2)h1->A[CB];                        MFMA Q11(a1,b1);
//     rd b0(t+1)<-B[OB]; rd a0(t+1)<-A[OB]
// vmcnt(6)@P2 leaves {B(t+2)h0,h1, A(t+2)h0} in flight and drains all of
// A(t+1),B(t+1) (issued >=3 phases earlier) before the P3 reads; the
// following barrier gives cross-wave visibility. Every LDS region is
// overwritten >=1 barrier after its last read.
#define KTILE(CB, OB, KT) do { \
    const int _k2 = ((KT) + 2 < NT) ? ((KT) + 2) * 64 : 0; \
    BAR(); \
    LOAD_B(b1, CB, 1); \
    SETP(1); MFMA_Q(a, b0, 0, 0); SETP(0); \
    BAR(); \
    STAGE_B(CB, 0, _k2); \
    SETP(1); MFMA_Q(a, b1, 0, 1); SETP(0); \
    SCHEDB(); \
    LOAD_A(a, CB, 1); \
    BAR(); \
    STAGE_B(CB, 1, _k2); \
    STAGE_A(CB, 0, _k2); \
    SETP(1); MFMA_Q(a, b0, 1, 0); SETP(0); \
    VMCNT(6); \
    BAR(); \
    STAGE_A(CB, 1, _k2); \
    SETP(1); MFMA_Q(a, b1, 1, 1); SETP(0); \
    SCHEDB(); \
    LOAD_B(b0, OB, 0); \
    LOAD_A(a, OB, 0); \
  } while (0)

    // prologue: stage A(0),B(0),B(1),A(1); drain A(0),B(0) only (vmcnt(8));
    // pre-read tile-0 fragments a0,b0.
    STAGE_A(0, 0, 0); STAGE_A(0, 1, 0);
    STAGE_B(0, 0, 0); STAGE_B(0, 1, 0);
    const int _k1 = (NT > 1) ? 64 : 0;
    STAGE_B(1, 0, _k1); STAGE_B(1, 1, _k1);
    STAGE_A(1, 0, _k1); STAGE_A(1, 1, _k1);
    VMCNT(8);
    BAR();
    LOAD_A(a, 0, 0);
    LOAD_B(b0, 0, 0);

    for (int kt = 0; kt < NT; kt += 2) {
        KTILE(0, 1, kt);
        KTILE(1, 0, kt + 1);
    }

#undef KTILE
#undef MFMA_Q
#undef LOAD_B
#undef LOAD_A
#undef STAGE_B
#undef STAGE_A

    // epilogue: C/D layout col=lane&15, row=(lane>>4)*4+reg
    const int crow = (lane >> 4) * 4;
    const int ccol = lane & 15;
#pragma unroll
    for (int mi = 0; mi < 8; ++mi) {
#pragma unroll
        for (int ni = 0; ni < 4; ++ni) {
#pragma unroll
            for (int rr = 0; rr < 4; ++rr) {
                size_t row = m0 + wm * 128 + mi * 16 + crow + rr;
                size_t col = n0 + wn * 64 + ni * 16 + ccol;
                size_t oix = row * (size_t)N + col;
                float v = acc[mi][ni][rr];
                if (EPI == 0)      outB[oix] = f2bfu(v);
                else if (EPI == 1) outF[oix] = v;
                else if (EPI == 2) outF[oix] = extra[oix] + v;
                else { float t = v > 0.f ? v : 0.f; outB[oix] = f2bfu(t * t); }
            }
        }
    }
}

// =====================================================================
// launcher
// =====================================================================
extern "C" void kernel_launch(void* const* d_in, const int* in_sizes, int n_in,
                              void* d_out, int out_size, void* d_ws, size_t ws_size,
                              hipStream_t stream) {
    const float* x    = (const float*)d_in[0];
    const float* ln1w = (const float*)d_in[2];
    const float* ln1b = (const float*)d_in[3];
    const float* ln2w = (const float*)d_in[4];
    const float* ln2b = (const float*)d_in[5];
    const float* w_r  = (const float*)d_in[6];
    // d_in[7] = w_k: unused by the reference's _wkv — skipped.
    const float* w_v  = (const float*)d_in[8];
    const float* w_o  = (const float*)d_in[9];
    const float* w_g  = (const float*)d_in[10];
    const float* ck_w = (const float*)d_in[11];
    const float* cv_w = (const float*)d_in[12];

    float* out0 = (float*)d_out;                       // x1 + ffn_out  [M,C]
    float* vout = out0 + (size_t)M_ * C_;              // v_first_out   [M,C] fp32

    char* ws = (char*)d_ws;
    const size_t MB = 1024ull * 1024ull;
    ushort_t* wr_bf = (ushort_t*)(ws + 0 * MB);        // 2MB
    ushort_t* wv_bf = (ushort_t*)(ws + 2 * MB);        // 2MB
    ushort_t* wo_bf = (ushort_t*)(ws + 4 * MB);        // 2MB
    ushort_t* ck_bf = (ushort_t*)(ws + 6 * MB);        // 8MB
    ushort_t* cv_bf = (ushort_t*)(ws + 14 * MB);       // 8MB
    float*    gate  = (float*)(ws + 22 * MB);          // 1MB
    ushort_t* zpage = (ushort_t*)(ws + 23 * MB);       // 16KB (1MB slot)
    ushort_t* bufA  = (ushort_t*)(ws + 24 * MB);       // 32MB  h1, later h2
    ushort_t* bufC  = (ushort_t*)(ws + 56 * MB);       // 32MB  x_comb
    ushort_t* r_bf  = (ushort_t*)(ws + 88 * MB);       // 32MB
    float*    x1    = (float*)(ws + 120 * MB);         // 64MB
    ushort_t* k2p   = (ushort_t*)(ws + 184 * MB);      // 128MB; total 312MB

    // weights fp32 -> bf16; zero page for shifted GEMM rows
    f2bf3_kernel<<<dim3(C_ * C_ / 1024, 3), 256, 0, stream>>>(w_r, w_v, w_o, wr_bf, wv_bf, wo_bf);
    f2bf2_kernel<<<dim3(FC_ * C_ / 1024, 2), 256, 0, stream>>>(ck_w, cv_w, ck_bf, cv_bf);
    hipMemsetAsync(zpage, 0, 16384, stream);

    // h = LN1(x)
    ln_kernel<<<M_, 256, 0, stream>>>(x, ln1w, ln1b, bufA);

    // gate = sigmoid((shift(h)-h) @ w_g^T)
    gate_kernel<<<M_, 256, 0, stream>>>(bufA, w_g, gate);

    // r = shift(h) @ w_r^T (bf16); v = shift(h) @ w_v^T (fp32, = output 1)
    gemm256<0, true><<<(M_ / 256) * (C_ / 256), 512, 0, stream>>>(bufA, wr_bf, nullptr, nullptr, r_bf, zpage, C_, C_);
    gemm256<1, true><<<(M_ / 256) * (C_ / 256), 512, 0, stream>>>(bufA, wv_bf, nullptr, vout, nullptr, zpage, C_, C_);

    // wkv fwd+bwd + combine -> x_comb
    wkv_combine_kernel<<<B_ * H_ * (T_ / 128), 256, 0, stream>>>(vout, r_bf, gate, bufC);

    // x1 = x + x_comb @ w_o^T
    gemm256<2, false><<<(M_ / 256) * (C_ / 256), 512, 0, stream>>>(bufC, wo_bf, x, x1, nullptr, zpage, C_, C_);

    // h2 = LN2(x1)
    ln_kernel<<<M_, 256, 0, stream>>>(x1, ln2w, ln2b, bufA);

    // k2p = relu(shift(h2) @ ck_w^T)^2; out0 = x1 + k2p @ cv_w^T
    gemm256<3, true><<<(M_ / 256) * (FC_ / 256), 512, 0, stream>>>(bufA, ck_bf, nullptr, nullptr, k2p, zpage, FC_, C_);
    gemm256<2, false><<<(M_ / 256) * (C_ / 256), 512, 0, stream>>>(k2p, cv_bf, x1, out0, nullptr, zpage, C_, FC_);
}

// Round 5
// 705.573 us; speedup vs baseline: 1.2813x; 1.0349x over previous
//
#include <hip/hip_runtime.h>

// ---- problem constants ----
constexpr int B_ = 8, T_ = 2048, C_ = 1024, H_ = 16, N_ = 64;
constexpr int M_ = B_ * T_;              // 16384 rows
constexpr int FC_ = 4 * C_;              // 4096

typedef __attribute__((ext_vector_type(8))) short bf16x8;
typedef __attribute__((ext_vector_type(4))) float f32x4;
typedef unsigned short ushort_t;
typedef unsigned int uint_t;

__device__ __forceinline__ float bfu2f(ushort_t u) {
    union { uint_t i; float f; } c; c.i = ((uint_t)u) << 16; return c.f;
}
__device__ __forceinline__ ushort_t f2bfu(float f) {
    union { float f; uint_t i; } c; c.f = f;
    uint_t i = c.i;
    uint_t r = i + 0x7FFFu + ((i >> 16) & 1u);   // round-to-nearest-even
    return (ushort_t)(r >> 16);
}

__device__ __forceinline__ void gl_lds16(const void* g, void* l) {
    __builtin_amdgcn_global_load_lds(
        (const __attribute__((address_space(1))) void*)g,
        (__attribute__((address_space(3))) void*)l, 16, 0, 0);
}

// =====================================================================
// fp32 -> bf16 weight converts, folded into 2 launches
// =====================================================================
__global__ __launch_bounds__(256) void f2bf3_kernel(const float* __restrict__ a,
                                                    const float* __restrict__ b,
                                                    const float* __restrict__ c,
                                                    ushort_t* __restrict__ oa,
                                                    ushort_t* __restrict__ ob,
                                                    ushort_t* __restrict__ oc) {
    const float* in = (blockIdx.y == 0) ? a : (blockIdx.y == 1) ? b : c;
    ushort_t* out   = (blockIdx.y == 0) ? oa : (blockIdx.y == 1) ? ob : oc;
    size_t i = ((size_t)blockIdx.x * 256 + threadIdx.x) * 4;
    float4 v = *(const float4*)(in + i);
    uint2 o;
    o.x = (uint_t)f2bfu(v.x) | ((uint_t)f2bfu(v.y) << 16);
    o.y = (uint_t)f2bfu(v.z) | ((uint_t)f2bfu(v.w) << 16);
    *(uint2*)(out + i) = o;
}

__global__ __launch_bounds__(256) void f2bf2_kernel(const float* __restrict__ a,
                                                    const float* __restrict__ b,
                                                    ushort_t* __restrict__ oa,
                                                    ushort_t* __restrict__ ob) {
    const float* in = (blockIdx.y == 0) ? a : b;
    ushort_t* out   = (blockIdx.y == 0) ? oa : ob;
    size_t i = ((size_t)blockIdx.x * 256 + threadIdx.x) * 4;
    float4 v = *(const float4*)(in + i);
    uint2 o;
    o.x = (uint_t)f2bfu(v.x) | ((uint_t)f2bfu(v.y) << 16);
    o.y = (uint_t)f2bfu(v.z) | ((uint_t)f2bfu(v.w) << 16);
    *(uint2*)(out + i) = o;
}

// =====================================================================
// LayerNorm over C=1024, one block per row, output bf16
// =====================================================================
__global__ __launch_bounds__(256) void ln_kernel(const float* __restrict__ x,
                                                 const float* __restrict__ w,
                                                 const float* __restrict__ b,
                                                 ushort_t* __restrict__ out) {
    const int row = blockIdx.x;
    const int tid = threadIdx.x;
    const float* xr = x + (size_t)row * C_;
    float4 xv = ((const float4*)xr)[tid];
    float s  = xv.x + xv.y + xv.z + xv.w;
    float ss = xv.x*xv.x + xv.y*xv.y + xv.z*xv.z + xv.w*xv.w;
#pragma unroll
    for (int off = 32; off; off >>= 1) { s += __shfl_down(s, off); ss += __shfl_down(ss, off); }
    __shared__ float sb[8];
    const int wv = tid >> 6, ln = tid & 63;
    if (ln == 0) { sb[wv] = s; sb[4 + wv] = ss; }
    __syncthreads();
    s  = sb[0] + sb[1] + sb[2] + sb[3];
    ss = sb[4] + sb[5] + sb[6] + sb[7];
    const float mean = s * (1.f / C_);
    const float var  = ss * (1.f / C_) - mean * mean;
    const float rstd = rsqrtf(var + 1e-5f);
    float4 wv4 = ((const float4*)w)[tid];
    float4 bv4 = ((const float4*)b)[tid];
    uint2 o;
    o.x = (uint_t)f2bfu((xv.x - mean) * rstd * wv4.x + bv4.x)
        | ((uint_t)f2bfu((xv.y - mean) * rstd * wv4.y + bv4.y) << 16);
    o.y = (uint_t)f2bfu((xv.z - mean) * rstd * wv4.z + bv4.z)
        | ((uint_t)f2bfu((xv.w - mean) * rstd * wv4.w + bv4.w) << 16);
    ((uint2*)(out + (size_t)row * C_))[tid] = o;
}

// =====================================================================
// gate[m,h] = sigmoid(dot(xx[m,:], w_g[h,:])), xx computed inline
// =====================================================================
__global__ __launch_bounds__(256) void gate_kernel(const ushort_t* __restrict__ h,
                                                   const float* __restrict__ wg,
                                                   float* __restrict__ gate) {
    __shared__ float xr[C_];
    const int row = blockIdx.x;
    const int tid = threadIdx.x;
    const int t = row & (T_ - 1);
    uint2 cu = *(const uint2*)(h + (size_t)row * C_ + tid * 4);
    uint2 pu = make_uint2(0u, 0u);
    if (t > 0) pu = *(const uint2*)(h + (size_t)(row - 1) * C_ + tid * 4);
    xr[tid * 4 + 0] = bfu2f((ushort_t)(pu.x & 0xffffu)) - bfu2f((ushort_t)(cu.x & 0xffffu));
    xr[tid * 4 + 1] = bfu2f((ushort_t)(pu.x >> 16))     - bfu2f((ushort_t)(cu.x >> 16));
    xr[tid * 4 + 2] = bfu2f((ushort_t)(pu.y & 0xffffu)) - bfu2f((ushort_t)(cu.y & 0xffffu));
    xr[tid * 4 + 3] = bfu2f((ushort_t)(pu.y >> 16))     - bfu2f((ushort_t)(cu.y >> 16));
    __syncthreads();
    const int wv = tid >> 6, ln = tid & 63;
#pragma unroll
    for (int hh = 0; hh < 4; ++hh) {
        const int h_ = wv * 4 + hh;
        const float* wrow = wg + (size_t)h_ * C_;
        float acc = 0.f;
#pragma unroll
        for (int i = 0; i < 16; ++i) { int c = i * 64 + ln; acc += xr[c] * wrow[c]; }
#pragma unroll
        for (int off = 32; off; off >>= 1) acc += __shfl_down(acc, off);
        if (ln == 0) gate[(size_t)row * H_ + h_] = 1.f / (1.f + __expf(-acc));
    }
}

// =====================================================================
// wkv fwd+bwd scan (decay 0.5), parallel LDS staging + 4 independent
// in-LDS scans + vectorized combine. Edge clamping reproduces warmup.
// =====================================================================
__global__ __launch_bounds__(256) void wkv_combine_kernel(const float* __restrict__ v,
                                                          const ushort_t* __restrict__ r,
                                                          const float* __restrict__ gate,
                                                          ushort_t* __restrict__ xc) {
    __shared__ float    vbuf[192 * 64];   // 48 KB, row i = t0-32+i (clamped)
    __shared__ ushort_t fb[128 * 64];     // 16 KB, fwd (bf16)
    __shared__ ushort_t bb[128 * 64];     // 16 KB, bwd (bf16)
    const int blk = blockIdx.x;           // b*256 + h*16 + chunk
    const int chunk = blk & 15;
    const int bh = blk >> 4;
    const int h = bh & 15;
    const int b = bh >> 4;
    const int t0 = chunk * 128;
    const int tid = threadIdx.x;

    // ---- phase 1: stage v[t0-32 .. t0+160) (clamped) into LDS ----
    {
        const float* vb = v + ((size_t)b * T_) * C_ + h * 64;
#pragma unroll
        for (int j = 0; j < 12; ++j) {
            int idx = j * 256 + tid;      // 0..3071
            int row = idx >> 4, q = idx & 15;
            int t = t0 - 32 + row;
            t = t < 0 ? 0 : (t > T_ - 1 ? T_ - 1 : t);
            float4 val = *(const float4*)(vb + (size_t)t * C_ + q * 4);
            *(float4*)(vbuf + row * 64 + q * 4) = val;
        }
    }
    __syncthreads();

    // ---- phase 2: 4 independent scans over LDS ----
    const int wv = tid >> 6, n = tid & 63;
    const int half = wv & 1;              // which 64-t half of the chunk
    if (wv < 2) {
        const int s = 64 * half;          // start row (t = t0-32+s)
        float carry = vbuf[s * 64 + n];
#pragma unroll
        for (int i = 1; i < 32; ++i)
            carry = 0.5f * (carry + vbuf[(s + i) * 64 + n]);
#pragma unroll 8
        for (int i = 32; i <= 95; ++i) {
            carry = 0.5f * (carry + vbuf[(s + i) * 64 + n]);
            int trel = s + i - 32;
            fb[trel * 64 + n] = f2bfu(carry);
        }
    } else {
        const int e = 64 * half + 127;    // start row (t = t0+64*half+95)
        float carry = vbuf[e * 64 + n];
#pragma unroll
        for (int i = 1; i < 32; ++i)
            carry = 0.5f * (carry + vbuf[(e - i) * 64 + n]);
#pragma unroll 8
        for (int i = 32; i <= 95; ++i) {
            carry = 0.5f * (carry + vbuf[(e - i) * 64 + n]);
            int trel = e - i - 32;
            bb[trel * 64 + n] = f2bfu(carry);
        }
    }
    __syncthreads();

    // ---- phase 3: combine xc = r * (g*fwd + (1-g)*bwd), vectorized x2 ----
    const size_t rowbase = ((size_t)b * T_ + t0) * C_ + h * 64;
    const size_t gbase = ((size_t)b * T_ + t0) * H_ + h;
#pragma unroll
    for (int i = 0; i < 16; ++i) {
        int idx = i * 512 + tid * 2;      // 0..8190, even
        int trow = idx >> 6, nn = idx & 63;
        uint_t fu = *(const uint_t*)(fb + idx);
        uint_t bu = *(const uint_t*)(bb + idx);
        uint_t ru = *(const uint_t*)(r + rowbase + (size_t)trow * C_ + nn);
        float g = gate[gbase + (size_t)trow * H_];
        float f0 = bfu2f((ushort_t)(fu & 0xffffu)), f1 = bfu2f((ushort_t)(fu >> 16));
        float b0 = bfu2f((ushort_t)(bu & 0xffffu)), b1 = bfu2f((ushort_t)(bu >> 16));
        float r0 = bfu2f((ushort_t)(ru & 0xffffu)), r1 = bfu2f((ushort_t)(ru >> 16));
        float o0 = r0 * (g * f0 + (1.f - g) * b0);
        float o1 = r1 * (g * f1 + (1.f - g) * b1);
        *(uint_t*)(xc + rowbase + (size_t)trow * C_ + nn) =
            (uint_t)f2bfu(o0) | ((uint_t)f2bfu(o1) << 16);
    }
}

// =====================================================================
// 256x256 pipelined bf16 GEMM. C[M,N] = A[M,K] * B[N,K]^T.
// 8 waves (2m x 4n), BK=64, 128KiB LDS dbuf, per wave 128x64 = acc[8][4].
// TWO phases per K-tile (32-MFMA clusters) -> 2 barrier crossings/tile
// instead of 4. Fragment reads sit between the barrier and the cluster
// (counted lgkmcnt); staging topology unchanged (A(t+1)->OB at PH0,
// B(t+2)->CB at PH1); single counted vmcnt(4)/tile followed by a barrier
// before any cross-wave read of the staged data (race-free by ledger).
// LDS swizzle byte^=(row&7)<<4 on reads; linear LDS dest + inverse-
// swizzled per-lane GLOBAL source for global_load_lds.
// SHIFT: A row m reads row m-1 (t==0 rows -> zero page).
// EPI: 0 bf16; 1 f32; 2 f32 extra+acc; 3 relu^2 bf16
// =====================================================================
#define BAR() do { asm volatile("" ::: "memory"); \
                   __builtin_amdgcn_s_barrier(); \
                   asm volatile("" ::: "memory"); } while (0)
#define SETP(x) __builtin_amdgcn_s_setprio(x)
#define SCHEDB() __builtin_amdgcn_sched_barrier(0)
#define VMCNT(n) asm volatile("s_waitcnt vmcnt(" #n ")" ::: "memory")

template <int EPI, bool SHIFT>
__global__ __launch_bounds__(512, 2) void gemm256(const ushort_t* __restrict__ A,
                                                  const ushort_t* __restrict__ Bm,
                                                  const float* __restrict__ extra,
                                                  float* __restrict__ outF,
                                                  ushort_t* __restrict__ outB,
                                                  const ushort_t* __restrict__ zpage,
                                                  int N, int K) {
    __shared__ ushort_t As[2][256 * 64];   // 64 KB
    __shared__ ushort_t Bs[2][256 * 64];   // 64 KB
    const int NT = K >> 6;                 // K-tiles (even >=2 for all shapes here)
    const int tid = threadIdx.x;
    const int lane = tid & 63, wv = tid >> 6;
    const int wm = wv >> 2, wn = wv & 3;   // 2 x 4 wave grid
    const size_t m0 = (size_t)(blockIdx.x & 63) * 256;   // Mtiles = 64 always
    const size_t n0 = (size_t)(blockIdx.x >> 6) * 256;

    // ---- staging: per-lane pre-swizzled global sources ----
    const int l8 = lane >> 3;
    const int swcol = ((lane & 7) ^ l8) * 8;   // elements
    const ushort_t* pA[2][2];
    const ushort_t* pB[2][2];
#pragma unroll
    for (int hf = 0; hf < 2; ++hf)
#pragma unroll
        for (int i8 = 0; i8 < 2; ++i8) {
            const size_t tr = (size_t)(hf * 128 + wv * 16 + i8 * 8 + l8);
            const size_t mrow = m0 + tr, nrow = n0 + tr;
            if (SHIFT)
                pA[hf][i8] = ((mrow & (size_t)(T_ - 1)) == 0)
                                 ? (zpage + swcol)
                                 : (A + (mrow - 1) * (size_t)K + swcol);
            else
                pA[hf][i8] = A + mrow * (size_t)K + swcol;
            pB[hf][i8] = Bm + nrow * (size_t)K + swcol;
        }

    // ---- swizzled fragment-read offsets ----
    const int rl = lane & 15;
    const int swz = (lane & 7) << 4;           // (row&7)<<4
    const int cq = (lane >> 4) << 4;           // (lane>>4)*16 bytes
    const int offk0 = cq ^ swz;                // kk=0
    const int offk1 = (64 | cq) ^ swz;         // kk=1 (+32 elements)
    const int aRow = (wm * 128 + rl) * 128;    // byte offset of frag row
    const int bRow = (wn * 64 + rl) * 128;

    bf16x8 a[8], b0[4], b1[4];
    f32x4 acc[8][4];
#pragma unroll
    for (int i = 0; i < 8; ++i)
#pragma unroll
        for (int j = 0; j < 4; ++j) acc[i][j] = (f32x4){0.f, 0.f, 0.f, 0.f};

#define STAGE_A(BUF, HF, KOF) do { \
    gl_lds16(pA[HF][0] + (KOF), &As[BUF][((HF) * 128 + wv * 16 + 0) * 64]); \
    gl_lds16(pA[HF][1] + (KOF), &As[BUF][((HF) * 128 + wv * 16 + 8) * 64]); } while (0)
#define STAGE_B(BUF, HF, KOF) do { \
    gl_lds16(pB[HF][0] + (KOF), &Bs[BUF][((HF) * 128 + wv * 16 + 0) * 64]); \
    gl_lds16(pB[HF][1] + (KOF), &Bs[BUF][((HF) * 128 + wv * 16 + 8) * 64]); } while (0)
#define LOAD_A(ARR, BUF, QM) do { \
    const char* _ab = (const char*)As[BUF] + aRow + (QM) * 64 * 128; \
    _Pragma("unroll") \
    for (int mi = 0; mi < 4; ++mi) { \
        ARR[mi * 2 + 0] = *(const bf16x8*)(_ab + mi * 16 * 128 + offk0); \
        ARR[mi * 2 + 1] = *(const bf16x8*)(_ab + mi * 16 * 128 + offk1); } } while (0)
#define LOAD_B(ARR, BUF, QN) do { \
    const char* _bb = (const char*)Bs[BUF] + bRow + (QN) * 32 * 128; \
    _Pragma("unroll") \
    for (int ni = 0; ni < 2; ++ni) { \
        ARR[ni * 2 + 0] = *(const bf16x8*)(_bb + ni * 16 * 128 + offk0); \
        ARR[ni * 2 + 1] = *(const bf16x8*)(_bb + ni * 16 * 128 + offk1); } } while (0)
#define MFMA_Q(AARR, BARR, QM, QN) do { \
    _Pragma("unroll") \
    for (int mi = 0; mi < 4; ++mi) \
    _Pragma("unroll") \
    for (int ni = 0; ni < 2; ++ni) { \
        acc[(QM)*4+mi][(QN)*2+ni] = __builtin_amdgcn_mfma_f32_16x16x32_bf16( \
            AARR[mi*2+0], BARR[ni*2+0], acc[(QM)*4+mi][(QN)*2+ni], 0, 0, 0); \
        acc[(QM)*4+mi][(QN)*2+ni] = __builtin_amdgcn_mfma_f32_16x16x32_bf16( \
            AARR[mi*2+1], BARR[ni*2+1], acc[(QM)*4+mi][(QN)*2+ni], 0, 0, 0); } } while (0)

// Tile t (CB=t&1, OB=CB^1), 2 phases:
// PH0: BAR; rd a0,b0,b1(t)<-CB [16]; st A(t+1)->OB; MFMA Q00+Q01 [32];
//      rd a1(t)<-CB [8]
// PH1: BAR; st B(t+2)->CB; MFMA Q10+Q11 [32]; vmcnt(4)
// Ledger: vmcnt(4)@t.PH1 leaves only B(t+2) in flight -> A(t+1) [t.PH0]
// and B(t+1) [t-1.PH1] landed; barrier at t+1.PH0 precedes their reads
// (cross-wave safe). Regions overwritten >=1 barrier after last read:
// OB.A (a1(t-1) read t-1.PH0, completed by t-1.PH1 lgkm) staged t.PH0;
// CB.B (b0/b1(t) read t.PH0) staged t.PH1.
#define KTILE(CB, OB, KT) do { \
    const int _kA = ((KT) + 1 < NT) ? ((KT) + 1) * 64 : 0; \
    const int _kB = ((KT) + 2 < NT) ? ((KT) + 2) * 64 : 0; \
    BAR(); \
    LOAD_A(a, CB, 0); \
    LOAD_B(b0, CB, 0); \
    LOAD_B(b1, CB, 1); \
    STAGE_A(OB, 0, _kA); \
    STAGE_A(OB, 1, _kA); \
    SETP(1); MFMA_Q(a, b0, 0, 0); MFMA_Q(a, b1, 0, 1); SETP(0); \
    SCHEDB(); \
    LOAD_A(a, CB, 1); \
    BAR(); \
    STAGE_B(CB, 0, _kB); \
    STAGE_B(CB, 1, _kB); \
    SETP(1); MFMA_Q(a, b0, 1, 0); MFMA_Q(a, b1, 1, 1); SETP(0); \
    VMCNT(4); \
  } while (0)

    // prologue: stage A(0),B(0),B(1); vmcnt(4) drains A(0),B(0) (leaves
    // B(1) in flight). First KTILE's BAR gives cross-wave visibility.
    STAGE_A(0, 0, 0); STAGE_A(0, 1, 0);
    STAGE_B(0, 0, 0); STAGE_B(0, 1, 0);
    const int _k1 = (NT > 1) ? 64 : 0;
    STAGE_B(1, 0, _k1); STAGE_B(1, 1, _k1);
    VMCNT(4);

    for (int kt = 0; kt < NT; kt += 2) {
        KTILE(0, 1, kt);
        KTILE(1, 0, kt + 1);
    }
    VMCNT(0);   // drain tail dummy LDS-DMA before block exit

#undef KTILE
#undef MFMA_Q
#undef LOAD_B
#undef LOAD_A
#undef STAGE_B
#undef STAGE_A

    // epilogue: C/D layout col=lane&15, row=(lane>>4)*4+reg
    const int crow = (lane >> 4) * 4;
    const int ccol = lane & 15;
#pragma unroll
    for (int mi = 0; mi < 8; ++mi) {
#pragma unroll
        for (int ni = 0; ni < 4; ++ni) {
#pragma unroll
            for (int rr = 0; rr < 4; ++rr) {
                size_t row = m0 + wm * 128 + mi * 16 + crow + rr;
                size_t col = n0 + wn * 64 + ni * 16 + ccol;
                size_t oix = row * (size_t)N + col;
                float v = acc[mi][ni][rr];
                if (EPI == 0)      outB[oix] = f2bfu(v);
                else if (EPI == 1) outF[oix] = v;
                else if (EPI == 2) outF[oix] = extra[oix] + v;
                else { float t = v > 0.f ? v : 0.f; outB[oix] = f2bfu(t * t); }
            }
        }
    }
}

// =====================================================================
// launcher
// =====================================================================
extern "C" void kernel_launch(void* const* d_in, const int* in_sizes, int n_in,
                              void* d_out, int out_size, void* d_ws, size_t ws_size,
                              hipStream_t stream) {
    const float* x    = (const float*)d_in[0];
    const float* ln1w = (const float*)d_in[2];
    const float* ln1b = (const float*)d_in[3];
    const float* ln2w = (const float*)d_in[4];
    const float* ln2b = (const float*)d_in[5];
    const float* w_r  = (const float*)d_in[6];
    // d_in[7] = w_k: unused by the reference's _wkv — skipped.
    const float* w_v  = (const float*)d_in[8];
    const float* w_o  = (const float*)d_in[9];
    const float* w_g  = (const float*)d_in[10];
    const float* ck_w = (const float*)d_in[11];
    const float* cv_w = (const float*)d_in[12];

    float* out0 = (float*)d_out;                       // x1 + ffn_out  [M,C]
    float* vout = out0 + (size_t)M_ * C_;              // v_first_out   [M,C] fp32

    char* ws = (char*)d_ws;
    const size_t MB = 1024ull * 1024ull;
    ushort_t* wr_bf = (ushort_t*)(ws + 0 * MB);        // 2MB
    ushort_t* wv_bf = (ushort_t*)(ws + 2 * MB);        // 2MB
    ushort_t* wo_bf = (ushort_t*)(ws + 4 * MB);        // 2MB
    ushort_t* ck_bf = (ushort_t*)(ws + 6 * MB);        // 8MB
    ushort_t* cv_bf = (ushort_t*)(ws + 14 * MB);       // 8MB
    float*    gate  = (float*)(ws + 22 * MB);          // 1MB
    ushort_t* zpage = (ushort_t*)(ws + 23 * MB);       // 16KB (1MB slot)
    ushort_t* bufA  = (ushort_t*)(ws + 24 * MB);       // 32MB  h1, later h2
    ushort_t* bufC  = (ushort_t*)(ws + 56 * MB);       // 32MB  x_comb
    ushort_t* r_bf  = (ushort_t*)(ws + 88 * MB);       // 32MB
    float*    x1    = (float*)(ws + 120 * MB);         // 64MB
    ushort_t* k2p   = (ushort_t*)(ws + 184 * MB);      // 128MB; total 312MB

    // weights fp32 -> bf16; zero page for shifted GEMM rows
    f2bf3_kernel<<<dim3(C_ * C_ / 1024, 3), 256, 0, stream>>>(w_r, w_v, w_o, wr_bf, wv_bf, wo_bf);
    f2bf2_kernel<<<dim3(FC_ * C_ / 1024, 2), 256, 0, stream>>>(ck_w, cv_w, ck_bf, cv_bf);
    hipMemsetAsync(zpage, 0, 16384, stream);

    // h = LN1(x)
    ln_kernel<<<M_, 256, 0, stream>>>(x, ln1w, ln1b, bufA);

    // gate = sigmoid((shift(h)-h) @ w_g^T)
    gate_kernel<<<M_, 256, 0, stream>>>(bufA, w_g, gate);

    // r = shift(h) @ w_r^T (bf16); v = shift(h) @ w_v^T (fp32, = output 1)
    gemm256<0, true><<<(M_ / 256) * (C_ / 256), 512, 0, stream>>>(bufA, wr_bf, nullptr, nullptr, r_bf, zpage, C_, C_);
    gemm256<1, true><<<(M_ / 256) * (C_ / 256), 512, 0, stream>>>(bufA, wv_bf, nullptr, vout, nullptr, zpage, C_, C_);

    // wkv fwd+bwd + combine -> x_comb
    wkv_combine_kernel<<<B_ * H_ * (T_ / 128), 256, 0, stream>>>(vout, r_bf, gate, bufC);

    // x1 = x + x_comb @ w_o^T
    gemm256<2, false><<<(M_ / 256) * (C_ / 256), 512, 0, stream>>>(bufC, wo_bf, x, x1, nullptr, zpage, C_, C_);

    // h2 = LN2(x1)
    ln_kernel<<<M_, 256, 0, stream>>>(x1, ln2w, ln2b, bufA);

    // k2p = relu(shift(h2) @ ck_w^T)^2; out0 = x1 + k2p @ cv_w^T
    gemm256<3, true><<<(M_ / 256) * (FC_ / 256), 512, 0, stream>>>(bufA, ck_bf, nullptr, nullptr, k2p, zpage, FC_, C_);
    gemm256<2, false><<<(M_ / 256) * (C_ / 256), 512, 0, stream>>>(k2p, cv_bf, x1, out0, nullptr, zpage, C_, FC_);
}